// Round 1
// baseline (659.434 us; speedup 1.0000x reference)
//
#include <hip/hip_runtime.h>
#include <hip/hip_bf16.h>
#include <cstdint>
#include <cstddef>

#define BB 4
#define CC 128
#define NN 8192
#define KK 16
#define HH 64
#define MM 32
#define C2 256

__device__ __forceinline__ unsigned short f2bf(float f){
    unsigned int x = __float_as_uint(f);
    x += 0x7fffu + ((x >> 16) & 1u);
    return (unsigned short)(x >> 16);
}
__device__ __forceinline__ float lo16(unsigned int u){ return __uint_as_float(u << 16); }
__device__ __forceinline__ float hi16(unsigned int u){ return __uint_as_float(u & 0xffff0000u); }

// ---------------- K1: pe = de_w2 @ gelu(bn(de_w1 @ theta_max)) + de_b2 ------
// thread-per-point, writes pe_t in (B,N,128) f32
__global__ __launch_bounds__(64) void k_pe(
    const float* __restrict__ dp, const float* __restrict__ dirs,
    const float* __restrict__ w1,
    const float* __restrict__ bng, const float* __restrict__ bnb,
    const float* __restrict__ bnm, const float* __restrict__ bnv,
    const float* __restrict__ w2, const float* __restrict__ b2,
    float* __restrict__ pe_t)
{
    __shared__ float s_dir[MM*3];
    __shared__ float s_w1[HH*MM];
    __shared__ float s_w2[CC*HH];
    __shared__ float s_sc[HH], s_sh[HH];
    __shared__ float s_b2[CC];
    const int tid = threadIdx.x;
    if (tid < MM){
        float x=dirs[tid*3+0], y=dirs[tid*3+1], z=dirs[tid*3+2];
        float inv = 1.0f / fmaxf(sqrtf(x*x+y*y+z*z), 1e-12f);
        s_dir[tid*3+0]=x*inv; s_dir[tid*3+1]=y*inv; s_dir[tid*3+2]=z*inv;
    }
    for (int i=tid;i<HH*MM;i+=64) s_w1[i]=w1[i];
    for (int i=tid;i<CC*HH;i+=64) s_w2[i]=w2[i];
    if (tid < HH){
        float sc = bng[tid] / sqrtf(bnv[tid] + 1e-5f);
        s_sc[tid]=sc; s_sh[tid]=bnb[tid]-bnm[tid]*sc;
    }
    for (int i=tid;i<CC;i+=64) s_b2[i]=b2[i];
    __syncthreads();

    const int p = blockIdx.x*64 + tid;
    const int b = p >> 13, n = p & (NN-1);
    const float* base = dp + ((size_t)b*3*NN + n)*KK;
    float nx[KK], ny[KK], nz[KK];
    #pragma unroll
    for (int k=0;k<KK;k++){
        float x = base[k];
        float y = base[(size_t)NN*KK + k];
        float z = base[2*(size_t)NN*KK + k];
        float inv = 1.0f / fmaxf(sqrtf(x*x+y*y+z*z), 1e-12f);
        nx[k]=x*inv; ny[k]=y*inv; nz[k]=z*inv;
    }
    float tmax[MM];
    #pragma unroll
    for (int m=0;m<MM;m++){
        float vx=s_dir[m*3], vy=s_dir[m*3+1], vz=s_dir[m*3+2];
        float t = -1e30f;
        #pragma unroll
        for (int k=0;k<KK;k++)
            t = fmaxf(t, vx*nx[k]+vy*ny[k]+vz*nz[k]);
        tmax[m]=t;
    }
    float h[HH];
    #pragma unroll
    for (int j=0;j<HH;j++){
        const float4* wr = (const float4*)(s_w1 + j*MM);
        float a0=0.f,a1=0.f,a2=0.f,a3=0.f;
        #pragma unroll
        for (int q=0;q<MM/4;q++){
            float4 w = wr[q];
            a0 += w.x*tmax[4*q+0]; a1 += w.y*tmax[4*q+1];
            a2 += w.z*tmax[4*q+2]; a3 += w.w*tmax[4*q+3];
        }
        float a = (a0+a1)+(a2+a3);
        a = a*s_sc[j] + s_sh[j];
        h[j] = 0.5f*a*(1.0f+erff(a*0.7071067811865475f));
    }
    float* outp = pe_t + (size_t)p*CC;
    #pragma unroll 4
    for (int c=0;c<CC;c+=4){
        float r[4];
        #pragma unroll
        for (int i=0;i<4;i++){
            const float4* wr = (const float4*)(s_w2 + (c+i)*HH);
            float a0=0.f,a1=0.f,a2=0.f,a3=0.f;
            #pragma unroll
            for (int q=0;q<HH/4;q++){
                float4 w = wr[q];
                a0 += w.x*h[4*q+0]; a1 += w.y*h[4*q+1];
                a2 += w.z*h[4*q+2]; a3 += w.w*h[4*q+3];
            }
            r[i] = (a0+a1)+(a2+a3) + s_b2[c+i];
        }
        float4 o; o.x=r[0]; o.y=r[1]; o.z=r[2]; o.w=r[3];
        *(float4*)(outp + c) = o;
    }
}

// ---------------- K2: f1/f2/f3 = l_wX @ f + l_bX -----------------------------
// thread-per-point; blockIdx.y selects matrix; f1,f2 -> g12 (B,N,256) bf16
// interleaved; f3 -> f3t (B,N,128) bf16
__global__ __launch_bounds__(64) void k_lin3(
    const float* __restrict__ f,
    const float* __restrict__ w1g, const float* __restrict__ b1g,
    const float* __restrict__ w2g, const float* __restrict__ b2g,
    const float* __restrict__ w3g, const float* __restrict__ b3g,
    unsigned short* __restrict__ g12, unsigned short* __restrict__ f3t)
{
    __shared__ alignas(16) unsigned short s_w[CC*CC];
    __shared__ float s_bias[CC];
    const int tid = threadIdx.x;
    const int mat = blockIdx.y;
    const float* Wg = (mat==0)? w1g : (mat==1)? w2g : w3g;
    const float* Bg = (mat==0)? b1g : (mat==1)? b2g : b3g;
    for (int i = tid*4; i < CC*CC; i += 64*4){
        float4 w = *(const float4*)(Wg + i);
        ushort4 u; u.x=f2bf(w.x); u.y=f2bf(w.y); u.z=f2bf(w.z); u.w=f2bf(w.w);
        *(ushort4*)(s_w + i) = u;
    }
    for (int i=tid;i<CC;i+=64) s_bias[i]=Bg[i];
    __syncthreads();

    const int p = blockIdx.x*64 + tid;
    const int b = p >> 13, n = p & (NN-1);
    const float* fcol = f + (size_t)b*CC*NN + n;
    float fr[CC];
    #pragma unroll
    for (int c=0;c<CC;c++) fr[c] = fcol[(size_t)c*NN];

    size_t obase = (mat==0) ? ((size_t)p*C2)
                 : (mat==1) ? ((size_t)p*C2 + CC)
                            : ((size_t)p*CC);
    unsigned short* outp = (mat==2) ? (f3t + obase) : (g12 + obase);
    for (int o=0;o<CC;o+=4){
        unsigned short us[4];
        #pragma unroll
        for (int i=0;i<4;i++){
            const uint4* wr = (const uint4*)(s_w + (o+i)*CC);
            float a0=0.f,a1=0.f,a2=0.f,a3=0.f;
            #pragma unroll
            for (int q=0;q<CC/8;q++){
                uint4 w = wr[q];
                a0 += lo16(w.x)*fr[8*q+0]; a1 += hi16(w.x)*fr[8*q+1];
                a2 += lo16(w.y)*fr[8*q+2]; a3 += hi16(w.y)*fr[8*q+3];
                a0 += lo16(w.z)*fr[8*q+4]; a1 += hi16(w.z)*fr[8*q+5];
                a2 += lo16(w.w)*fr[8*q+6]; a3 += hi16(w.w)*fr[8*q+7];
            }
            us[i] = f2bf((a0+a1)+(a2+a3) + s_bias[o+i]);
        }
        ushort4 u; u.x=us[0]; u.y=us[1]; u.z=us[2]; u.w=us[3];
        *(ushort4*)(outp + o) = u;
    }
}

// ---------------- K3: knn gather-max + combine + BN + residual --------------
// warp-per-point; lanes 0..63 span the 256 interleaved channels (f1|f2)
__global__ __launch_bounds__(256) void k_gather(
    const float* __restrict__ f,
    const int* __restrict__ qidx,
    const unsigned short* __restrict__ g12,
    const unsigned short* __restrict__ f3t,
    const float* __restrict__ pe_t,
    const float* __restrict__ bn_g, const float* __restrict__ bn_b,
    const float* __restrict__ bn_m, const float* __restrict__ bn_v,
    float* __restrict__ fmid)
{
    const int lane = threadIdx.x & 63;
    const int wrp  = threadIdx.x >> 6;
    const int p = blockIdx.x*4 + wrp;
    const int b = p >> 13, n = p & (NN-1);
    const int* idxp = qidx + (size_t)p*KK;

    uint2 sv = *(const uint2*)(g12 + (size_t)p*C2 + lane*4);
    float s0 = lo16(sv.x), s1 = hi16(sv.x), s2 = lo16(sv.y), s3 = hi16(sv.y);

    float a0=-3.0e38f, a1=-3.0e38f, a2=-3.0e38f, a3=-3.0e38f;
    const unsigned short* gb = g12 + (size_t)b*NN*C2 + lane*4;
    #pragma unroll
    for (int k=0;k<KK;k++){
        int j = idxp[k];
        uint2 gv = *(const uint2*)(gb + (size_t)j*C2);
        a0 = fmaxf(a0, lo16(gv.x)); a1 = fmaxf(a1, hi16(gv.x));
        a2 = fmaxf(a2, lo16(gv.y)); a3 = fmaxf(a3, hi16(gv.y));
    }
    // lanes >= 32 hold f2 channels: agg2 = max + f2_self
    if (lane >= 32){ a0 += s0; a1 += s1; a2 += s2; a3 += s3; }
    float c0v = a0 + __shfl_xor(a0, 32);
    float c1v = a1 + __shfl_xor(a1, 32);
    float c2v = a2 + __shfl_xor(a2, 32);
    float c3v = a3 + __shfl_xor(a3, 32);
    if (lane < 32){
        const int ch = lane*4;
        uint2 f3v = *(const uint2*)(f3t + (size_t)p*CC + ch);
        float s[4] = { c0v + lo16(f3v.x), c1v + hi16(f3v.x),
                       c2v + lo16(f3v.y), c3v + hi16(f3v.y) };
        float4 g4 = *(const float4*)(bn_g + ch);
        float4 b4 = *(const float4*)(bn_b + ch);
        float4 m4 = *(const float4*)(bn_m + ch);
        float4 v4 = *(const float4*)(bn_v + ch);
        float4 pe4 = *(const float4*)(pe_t + (size_t)p*CC + ch);
        const float gg[4]={g4.x,g4.y,g4.z,g4.w}, bbv[4]={b4.x,b4.y,b4.z,b4.w},
                    mmv[4]={m4.x,m4.y,m4.z,m4.w}, vvv[4]={v4.x,v4.y,v4.z,v4.w},
                    ppv[4]={pe4.x,pe4.y,pe4.z,pe4.w};
        const float* fc = f    + ((size_t)b*CC + ch)*NN + n;
        float*       oc = fmid + ((size_t)b*CC + ch)*NN + n;
        #pragma unroll
        for (int i=0;i<4;i++){
            float sc = gg[i] / sqrtf(vvv[i] + 1e-5f);
            float bnval = (s[i]-mmv[i])*sc + bbv[i];
            oc[(size_t)i*NN] = fc[(size_t)i*NN] + bnval + ppv[i];
        }
    }
}

// ---------------- K4: h2 = gelu(bn(m_w1 @ fmid)) ----------------------------
// thread-per-point; blockIdx.y = half of the 256 output channels
__global__ __launch_bounds__(64) void k_h2(
    const float* __restrict__ fmid,
    const float* __restrict__ w1g,
    const float* __restrict__ bng, const float* __restrict__ bnb,
    const float* __restrict__ bnm, const float* __restrict__ bnv,
    float* __restrict__ h2)
{
    __shared__ alignas(16) unsigned short s_w[128*CC];
    __shared__ float s_sc[128], s_sh[128];
    const int tid = threadIdx.x;
    const int jh = blockIdx.y;
    const float* Wg = w1g + (size_t)jh*128*CC;
    for (int i=tid*4;i<128*CC;i+=64*4){
        float4 w = *(const float4*)(Wg + i);
        ushort4 u; u.x=f2bf(w.x);u.y=f2bf(w.y);u.z=f2bf(w.z);u.w=f2bf(w.w);
        *(ushort4*)(s_w + i) = u;
    }
    for (int i=tid;i<128;i+=64){
        int jg = jh*128 + i;
        float sc = bng[jg] / sqrtf(bnv[jg] + 1e-5f);
        s_sc[i]=sc; s_sh[i]=bnb[jg]-bnm[jg]*sc;
    }
    __syncthreads();
    const int p = blockIdx.x*64 + tid;
    const int b = p >> 13, n = p & (NN-1);
    const float* fcol = fmid + (size_t)b*CC*NN + n;
    float fr[CC];
    #pragma unroll
    for (int c=0;c<CC;c++) fr[c]=fcol[(size_t)c*NN];
    float* ocol = h2 + ((size_t)b*C2 + jh*128)*NN + n;
    for (int j=0;j<128;j++){
        const uint4* wr = (const uint4*)(s_w + j*CC);
        float a0=0.f,a1=0.f,a2=0.f,a3=0.f;
        #pragma unroll
        for (int q=0;q<CC/8;q++){
            uint4 w = wr[q];
            a0 += lo16(w.x)*fr[8*q+0]; a1 += hi16(w.x)*fr[8*q+1];
            a2 += lo16(w.y)*fr[8*q+2]; a3 += hi16(w.y)*fr[8*q+3];
            a0 += lo16(w.z)*fr[8*q+4]; a1 += hi16(w.z)*fr[8*q+5];
            a2 += lo16(w.w)*fr[8*q+6]; a3 += hi16(w.w)*fr[8*q+7];
        }
        float a = (a0+a1)+(a2+a3);
        a = a*s_sc[j] + s_sh[j];
        a = 0.5f*a*(1.0f+erff(a*0.7071067811865475f));
        ocol[(size_t)j*NN] = a;
    }
}

// ---------------- K5: out = fmid + m_w2 @ h2 --------------------------------
// thread-per-point; blockIdx.y = half of the 128 output channels
__global__ __launch_bounds__(64) void k_out(
    const float* __restrict__ fmid,
    const float* __restrict__ h2,
    const float* __restrict__ w2g,
    float* __restrict__ out)
{
    __shared__ alignas(16) unsigned short s_wt[C2*64]; // [j][c_local]
    const int tid = threadIdx.x;
    const int ch0 = blockIdx.y * 64;
    for (int i = tid; i < C2*64; i += 64){
        int j = i >> 6, cl = i & 63;
        s_wt[i] = f2bf(w2g[(size_t)(ch0+cl)*C2 + j]);
    }
    __syncthreads();
    const int p = blockIdx.x*64 + tid;
    const int b = p >> 13, n = p & (NN-1);
    const float* hcol = h2 + (size_t)b*C2*NN + n;
    float acc[64];
    #pragma unroll
    for (int c=0;c<64;c++) acc[c]=0.f;
    #pragma unroll 4
    for (int j=0;j<C2;j++){
        float hv = hcol[(size_t)j*NN];
        const uint4* wr = (const uint4*)(s_wt + j*64);
        #pragma unroll
        for (int q=0;q<8;q++){
            uint4 w = wr[q];
            acc[8*q+0] += lo16(w.x)*hv; acc[8*q+1] += hi16(w.x)*hv;
            acc[8*q+2] += lo16(w.y)*hv; acc[8*q+3] += hi16(w.y)*hv;
            acc[8*q+4] += lo16(w.z)*hv; acc[8*q+5] += hi16(w.z)*hv;
            acc[8*q+6] += lo16(w.w)*hv; acc[8*q+7] += hi16(w.w)*hv;
        }
    }
    const float* fc = fmid + ((size_t)b*CC + ch0)*NN + n;
    float*       oc = out  + ((size_t)b*CC + ch0)*NN + n;
    #pragma unroll
    for (int c=0;c<64;c++) oc[(size_t)c*NN] = fc[(size_t)c*NN] + acc[c];
}

extern "C" void kernel_launch(void* const* d_in, const int* in_sizes, int n_in,
                              void* d_out, int out_size, void* d_ws, size_t ws_size,
                              hipStream_t stream)
{
    const float* f      = (const float*)d_in[0];
    const float* dp     = (const float*)d_in[1];
    const int*   qidx   = (const int*)  d_in[2];
    const float* dirs   = (const float*)d_in[3];
    const float* de_w1  = (const float*)d_in[4];
    const float* de_bng = (const float*)d_in[5];
    const float* de_bnb = (const float*)d_in[6];
    const float* de_bnm = (const float*)d_in[7];
    const float* de_bnv = (const float*)d_in[8];
    const float* de_w2  = (const float*)d_in[9];
    const float* de_b2  = (const float*)d_in[10];
    const float* l_w1   = (const float*)d_in[11];
    const float* l_b1   = (const float*)d_in[12];
    const float* l_w2   = (const float*)d_in[13];
    const float* l_b2   = (const float*)d_in[14];
    const float* l_w3   = (const float*)d_in[15];
    const float* l_b3   = (const float*)d_in[16];
    const float* l_bng  = (const float*)d_in[17];
    const float* l_bnb  = (const float*)d_in[18];
    const float* l_bnm  = (const float*)d_in[19];
    const float* l_bnv  = (const float*)d_in[20];
    const float* m_w1   = (const float*)d_in[21];
    const float* m_bng  = (const float*)d_in[22];
    const float* m_bnb  = (const float*)d_in[23];
    const float* m_bnm  = (const float*)d_in[24];
    const float* m_bnv  = (const float*)d_in[25];
    const float* m_w2   = (const float*)d_in[26];

    char* ws = (char*)d_ws;
    // layout (bytes):
    //   pe_t  f32 (B,N,128):  [0,        16777216)
    //   g12   bf16(B,N,256):  [16777216, 33554432)
    //   h2    f32 (B,256,N):  [0,        33554432)   (aliases pe_t+g12, dead after K3)
    //   f3t   bf16(B,N,128):  [33554432, 41943040)
    //   fmid  f32 (B,128,N):  [41943040, 58720256)
    float*          pe_t = (float*)(ws + 0);
    unsigned short* g12  = (unsigned short*)(ws + 16777216);
    float*          h2   = (float*)(ws + 0);
    unsigned short* f3t  = (unsigned short*)(ws + 33554432);
    float*          fmid = (float*)(ws + 41943040);

    k_pe<<<dim3(512), dim3(64), 0, stream>>>(dp, dirs, de_w1, de_bng, de_bnb, de_bnm, de_bnv,
                                             de_w2, de_b2, pe_t);
    k_lin3<<<dim3(512,3), dim3(64), 0, stream>>>(f, l_w1, l_b1, l_w2, l_b2, l_w3, l_b3, g12, f3t);
    k_gather<<<dim3(8192), dim3(256), 0, stream>>>(f, qidx, g12, f3t, pe_t,
                                                   l_bng, l_bnb, l_bnm, l_bnv, fmid);
    k_h2<<<dim3(512,2), dim3(64), 0, stream>>>(fmid, m_w1, m_bng, m_bnb, m_bnm, m_bnv, h2);
    k_out<<<dim3(512,2), dim3(64), 0, stream>>>(fmid, h2, m_w2, (float*)d_out);
}

// Round 2
// 175.627 us; speedup vs baseline: 3.7548x; 3.7548x over previous
//
#include <hip/hip_runtime.h>
#include <hip/hip_bf16.h>
#include <cstdint>
#include <cstddef>

#define BB 4
#define CC 128
#define NN 8192
#define KK 16
#define HH 64
#define MM 32
#define C2 256

typedef __attribute__((ext_vector_type(8))) short bf16x8;
typedef __attribute__((ext_vector_type(4))) float f32x4;

__device__ __forceinline__ unsigned short f2bf(float f){
    unsigned int x = __float_as_uint(f);
    x += 0x7fffu + ((x >> 16) & 1u);
    return (unsigned short)(x >> 16);
}
__device__ __forceinline__ unsigned int pk2(float a, float b){
    return (unsigned int)f2bf(a) | ((unsigned int)f2bf(b) << 16);
}
__device__ __forceinline__ float lo16(unsigned int u){ return __uint_as_float(u << 16); }
__device__ __forceinline__ float hi16(unsigned int u){ return __uint_as_float(u & 0xffff0000u); }
__device__ __forceinline__ float gelu(float a){
    return 0.5f*a*(1.0f+erff(a*0.7071067811865475f));
}

// ---------------- K1: pe = de_w2 @ gelu(bn(de_w1 @ theta_max)) + de_b2 ------
// thread-per-point; blockIdx.y = half of 128 out channels; pe bf16 (B,N,128)
__global__ __launch_bounds__(64) void k_pe(
    const float* __restrict__ dp, const float* __restrict__ dirs,
    const float* __restrict__ w1,
    const float* __restrict__ bng, const float* __restrict__ bnb,
    const float* __restrict__ bnm, const float* __restrict__ bnv,
    const float* __restrict__ w2, const float* __restrict__ b2,
    unsigned short* __restrict__ pe)
{
    __shared__ float s_dir[MM*3];
    __shared__ float s_w1[HH*MM];
    __shared__ float s_w2[64*HH];   // half of de_w2
    __shared__ float s_sc[HH], s_sh[HH];
    __shared__ float s_b2[64];
    const int tid = threadIdx.x;
    const int jh = blockIdx.y;
    if (tid < MM){
        float x=dirs[tid*3+0], y=dirs[tid*3+1], z=dirs[tid*3+2];
        float inv = 1.0f / fmaxf(sqrtf(x*x+y*y+z*z), 1e-12f);
        s_dir[tid*3+0]=x*inv; s_dir[tid*3+1]=y*inv; s_dir[tid*3+2]=z*inv;
    }
    for (int i=tid;i<HH*MM;i+=64) s_w1[i]=w1[i];
    for (int i=tid;i<64*HH;i+=64) s_w2[i]=w2[(size_t)jh*64*HH + i];
    if (tid < HH){
        float sc = bng[tid] / sqrtf(bnv[tid] + 1e-5f);
        s_sc[tid]=sc; s_sh[tid]=bnb[tid]-bnm[tid]*sc;
    }
    if (tid < 64) s_b2[tid]=b2[jh*64+tid];
    __syncthreads();

    const int p = blockIdx.x*64 + tid;
    const int b = p >> 13, n = p & (NN-1);
    const float* base = dp + ((size_t)b*3*NN + n)*KK;
    float nx[KK], ny[KK], nz[KK];
    #pragma unroll
    for (int k=0;k<KK;k++){
        float x = base[k];
        float y = base[(size_t)NN*KK + k];
        float z = base[2*(size_t)NN*KK + k];
        float inv = 1.0f / fmaxf(sqrtf(x*x+y*y+z*z), 1e-12f);
        nx[k]=x*inv; ny[k]=y*inv; nz[k]=z*inv;
    }
    float tmax[MM];
    #pragma unroll
    for (int m=0;m<MM;m++){
        float vx=s_dir[m*3], vy=s_dir[m*3+1], vz=s_dir[m*3+2];
        float t = -1e30f;
        #pragma unroll
        for (int k=0;k<KK;k++)
            t = fmaxf(t, vx*nx[k]+vy*ny[k]+vz*nz[k]);
        tmax[m]=t;
    }
    float h[HH];
    #pragma unroll
    for (int j=0;j<HH;j++){
        const float4* wr = (const float4*)(s_w1 + j*MM);
        float a0=0.f,a1=0.f,a2=0.f,a3=0.f;
        #pragma unroll
        for (int q=0;q<MM/4;q++){
            float4 w = wr[q];
            a0 += w.x*tmax[4*q+0]; a1 += w.y*tmax[4*q+1];
            a2 += w.z*tmax[4*q+2]; a3 += w.w*tmax[4*q+3];
        }
        float a = (a0+a1)+(a2+a3);
        a = a*s_sc[j] + s_sh[j];
        h[j] = gelu(a);
    }
    unsigned short* outp = pe + (size_t)p*CC + jh*64;
    #pragma unroll 4
    for (int c=0;c<64;c+=4){
        float r[4];
        #pragma unroll
        for (int i=0;i<4;i++){
            const float4* wr = (const float4*)(s_w2 + (c+i)*HH);
            float a0=0.f,a1=0.f,a2=0.f,a3=0.f;
            #pragma unroll
            for (int q=0;q<HH/4;q++){
                float4 w = wr[q];
                a0 += w.x*h[4*q+0]; a1 += w.y*h[4*q+1];
                a2 += w.z*h[4*q+2]; a3 += w.w*h[4*q+3];
            }
            r[i] = (a0+a1)+(a2+a3) + s_b2[c+i];
        }
        ushort4 u; u.x=f2bf(r[0]); u.y=f2bf(r[1]); u.z=f2bf(r[2]); u.w=f2bf(r[3]);
        *(ushort4*)(outp + c) = u;
    }
}

// ---------------- K2: f1/f2/f3 MFMA GEMM ------------------------------------
// block 256 thr = 4 waves; tile M=128 x NT=64; K=128; mats looped in-block.
__global__ __launch_bounds__(256) void k_lin3(
    const float* __restrict__ f,
    const float* __restrict__ w1g, const float* __restrict__ b1g,
    const float* __restrict__ w2g, const float* __restrict__ b2g,
    const float* __restrict__ w3g, const float* __restrict__ b3g,
    unsigned short* __restrict__ g12, unsigned short* __restrict__ f3t)
{
    __shared__ alignas(16) unsigned short Xs[64*128];   // [n][c] bf16, swizzled
    __shared__ alignas(16) unsigned short Ws[128*128];  // [o][c] bf16, swizzled
    __shared__ float s_bias[128];
    const int tid = threadIdx.x;
    const int b  = blockIdx.x >> 7;
    const int n0 = (blockIdx.x & 127) * 64;

    // stage X tile transposed (f is (B,C,N) f32) via 4x4 reg transpose
    {
        const int j = (tid & 15) * 4;                 // local n base
        #pragma unroll
        for (int p = 0; p < 2; ++p){
            const int cb = ((tid >> 4) + p*16) * 4;   // c base
            const float* src = f + ((size_t)b*CC + cb)*NN + n0 + j;
            float4 r0 = *(const float4*)(src);
            float4 r1 = *(const float4*)(src + NN);
            float4 r2 = *(const float4*)(src + 2*(size_t)NN);
            float4 r3 = *(const float4*)(src + 3*(size_t)NN);
            const float rr[4][4] = {{r0.x,r1.x,r2.x,r3.x},{r0.y,r1.y,r2.y,r3.y},
                                    {r0.z,r1.z,r2.z,r3.z},{r0.w,r1.w,r2.w,r3.w}};
            #pragma unroll
            for (int i=0;i<4;i++){
                int n = j + i;
                int off = n*256 + ((cb*2) ^ ((n&7)<<4));
                uint2 v; v.x = pk2(rr[i][0], rr[i][1]); v.y = pk2(rr[i][2], rr[i][3]);
                *(uint2*)((char*)Xs + off) = v;
            }
        }
    }

    const int wid = tid >> 6, lane = tid & 63;
    const int lr = lane & 15, lg = lane >> 4;
    const int o0 = (wid >> 1) * 64;
    const int nl0 = (wid & 1) * 32;

    for (int mat = 0; mat < 3; ++mat){
        const float* Wg = (mat==0)? w1g : (mat==1)? w2g : w3g;
        const float* Bg = (mat==0)? b1g : (mat==1)? b2g : b3g;
        __syncthreads();   // prev compute done / Xs staged
        #pragma unroll 4
        for (int p = 0; p < 16; ++p){
            int o = (tid >> 5) + p*8;
            int c4 = (tid & 31) * 4;
            float4 w = *(const float4*)(Wg + (size_t)o*CC + c4);
            int off = o*256 + ((c4*2) ^ ((o&7)<<4));
            uint2 v; v.x = pk2(w.x, w.y); v.y = pk2(w.z, w.w);
            *(uint2*)((char*)Ws + off) = v;
        }
        if (tid < 128) s_bias[tid] = Bg[tid];
        __syncthreads();

        f32x4 acc[4][2];
        #pragma unroll
        for (int fi=0;fi<4;fi++){
            int o = o0 + fi*16 + lg*4;
            f32x4 bi = {s_bias[o], s_bias[o+1], s_bias[o+2], s_bias[o+3]};
            acc[fi][0] = bi; acc[fi][1] = bi;
        }
        #pragma unroll
        for (int kk=0; kk<4; ++kk){
            const int kb = kk*64 + lg*16;
            bf16x8 a[4], x[2];
            #pragma unroll
            for (int fi=0;fi<4;fi++){
                int row = o0 + fi*16 + lr;
                a[fi] = *(const bf16x8*)((const char*)Ws + row*256 + (kb ^ ((row&7)<<4)));
            }
            #pragma unroll
            for (int fj=0;fj<2;fj++){
                int nr = nl0 + fj*16 + lr;
                x[fj] = *(const bf16x8*)((const char*)Xs + nr*256 + (kb ^ ((nr&7)<<4)));
            }
            #pragma unroll
            for (int fi=0;fi<4;fi++)
                #pragma unroll
                for (int fj=0;fj<2;fj++)
                    acc[fi][fj] = __builtin_amdgcn_mfma_f32_16x16x32_bf16(a[fi], x[fj], acc[fi][fj], 0,0,0);
        }
        #pragma unroll
        for (int fi=0;fi<4;fi++){
            #pragma unroll
            for (int fj=0;fj<2;fj++){
                int o = o0 + fi*16 + lg*4;
                int n = n0 + nl0 + fj*16 + lr;
                ushort4 u;
                u.x = f2bf(acc[fi][fj].x); u.y = f2bf(acc[fi][fj].y);
                u.z = f2bf(acc[fi][fj].z); u.w = f2bf(acc[fi][fj].w);
                if (mat == 2)
                    *(ushort4*)(f3t + (size_t)(b*NN + n)*CC + o) = u;
                else
                    *(ushort4*)(g12 + (size_t)(b*NN + n)*C2 + mat*CC + o) = u;
            }
        }
    }
}

// ---------------- K3: knn gather-max + combine + BN + residual --------------
__global__ __launch_bounds__(256) void k_gather(
    const float* __restrict__ f,
    const int* __restrict__ qidx,
    const unsigned short* __restrict__ g12,
    const unsigned short* __restrict__ f3t,
    const unsigned short* __restrict__ pe,
    const float* __restrict__ bn_g, const float* __restrict__ bn_b,
    const float* __restrict__ bn_m, const float* __restrict__ bn_v,
    float* __restrict__ fmid, unsigned short* __restrict__ fmidb)
{
    const int lane = threadIdx.x & 63;
    const int wrp  = threadIdx.x >> 6;
    const int p = blockIdx.x*4 + wrp;
    const int b = p >> 13, n = p & (NN-1);
    const int* idxp = qidx + (size_t)p*KK;

    uint2 sv = *(const uint2*)(g12 + (size_t)p*C2 + lane*4);
    float s0 = lo16(sv.x), s1 = hi16(sv.x), s2 = lo16(sv.y), s3 = hi16(sv.y);

    float a0=-3.0e38f, a1=-3.0e38f, a2=-3.0e38f, a3=-3.0e38f;
    const unsigned short* gb = g12 + (size_t)b*NN*C2 + lane*4;
    #pragma unroll
    for (int k=0;k<KK;k++){
        int j = idxp[k];
        uint2 gv = *(const uint2*)(gb + (size_t)j*C2);
        a0 = fmaxf(a0, lo16(gv.x)); a1 = fmaxf(a1, hi16(gv.x));
        a2 = fmaxf(a2, lo16(gv.y)); a3 = fmaxf(a3, hi16(gv.y));
    }
    if (lane >= 32){ a0 += s0; a1 += s1; a2 += s2; a3 += s3; }
    float c0v = a0 + __shfl_xor(a0, 32);
    float c1v = a1 + __shfl_xor(a1, 32);
    float c2v = a2 + __shfl_xor(a2, 32);
    float c3v = a3 + __shfl_xor(a3, 32);
    if (lane < 32){
        const int ch = lane*4;
        uint2 f3v = *(const uint2*)(f3t + (size_t)p*CC + ch);
        uint2 pev = *(const uint2*)(pe  + (size_t)p*CC + ch);
        float s[4] = { c0v + lo16(f3v.x), c1v + hi16(f3v.x),
                       c2v + lo16(f3v.y), c3v + hi16(f3v.y) };
        float pv[4] = { lo16(pev.x), hi16(pev.x), lo16(pev.y), hi16(pev.y) };
        float4 g4 = *(const float4*)(bn_g + ch);
        float4 b4 = *(const float4*)(bn_b + ch);
        float4 m4 = *(const float4*)(bn_m + ch);
        float4 v4 = *(const float4*)(bn_v + ch);
        const float gg[4]={g4.x,g4.y,g4.z,g4.w}, bbv[4]={b4.x,b4.y,b4.z,b4.w},
                    mmv[4]={m4.x,m4.y,m4.z,m4.w}, vvv[4]={v4.x,v4.y,v4.z,v4.w};
        const float* fc = f    + ((size_t)b*CC + ch)*NN + n;
        float*       oc = fmid + ((size_t)b*CC + ch)*NN + n;
        float ov[4];
        #pragma unroll
        for (int i=0;i<4;i++){
            float sc = gg[i] / sqrtf(vvv[i] + 1e-5f);
            float bnval = (s[i]-mmv[i])*sc + bbv[i];
            float res = fc[(size_t)i*NN] + bnval + pv[i];
            oc[(size_t)i*NN] = res;
            ov[i] = res;
        }
        ushort4 u; u.x=f2bf(ov[0]); u.y=f2bf(ov[1]); u.z=f2bf(ov[2]); u.w=f2bf(ov[3]);
        *(ushort4*)(fmidb + (size_t)p*CC + ch) = u;
    }
}

// ---------------- K4: h2 = gelu(bn(m_w1 @ fmid)) MFMA -----------------------
// grid (512, 2): blockIdx.y = half of 256 out channels; h2 bf16 (B,N,256)
__global__ __launch_bounds__(256) void k_h2(
    const unsigned short* __restrict__ fmidb,
    const float* __restrict__ w1g,
    const float* __restrict__ bng, const float* __restrict__ bnb,
    const float* __restrict__ bnm, const float* __restrict__ bnv,
    unsigned short* __restrict__ h2)
{
    __shared__ alignas(16) unsigned short Xs[64*128];
    __shared__ alignas(16) unsigned short Ws[128*128];
    __shared__ float s_sc[128], s_sh[128];
    const int tid = threadIdx.x;
    const int b  = blockIdx.x >> 7;
    const int n0 = (blockIdx.x & 127) * 64;
    const int jh = blockIdx.y;

    #pragma unroll
    for (int p=0;p<4;p++){
        int n = (tid>>4) + p*16;
        int c8 = (tid&15)*8;
        uint4 v = *(const uint4*)(fmidb + (size_t)(b*NN + n0 + n)*CC + c8);
        int off = n*256 + ((c8*2) ^ ((n&7)<<4));
        *(uint4*)((char*)Xs + off) = v;
    }
    const float* Wg = w1g + (size_t)jh*128*CC;
    #pragma unroll 4
    for (int p = 0; p < 16; ++p){
        int o = (tid >> 5) + p*8;
        int c4 = (tid & 31) * 4;
        float4 w = *(const float4*)(Wg + (size_t)o*CC + c4);
        int off = o*256 + ((c4*2) ^ ((o&7)<<4));
        uint2 v; v.x = pk2(w.x, w.y); v.y = pk2(w.z, w.w);
        *(uint2*)((char*)Ws + off) = v;
    }
    if (tid < 128){
        int jg = jh*128 + tid;
        float sc = bng[jg] / sqrtf(bnv[jg] + 1e-5f);
        s_sc[tid] = sc; s_sh[tid] = bnb[jg] - bnm[jg]*sc;
    }
    __syncthreads();

    const int wid = tid >> 6, lane = tid & 63;
    const int lr = lane & 15, lg = lane >> 4;
    const int o0 = (wid >> 1) * 64;
    const int nl0 = (wid & 1) * 32;

    f32x4 acc[4][2];
    #pragma unroll
    for (int fi=0;fi<4;fi++){ acc[fi][0]=(f32x4){0,0,0,0}; acc[fi][1]=(f32x4){0,0,0,0}; }
    #pragma unroll
    for (int kk=0; kk<4; ++kk){
        const int kb = kk*64 + lg*16;
        bf16x8 a[4], x[2];
        #pragma unroll
        for (int fi=0;fi<4;fi++){
            int row = o0 + fi*16 + lr;
            a[fi] = *(const bf16x8*)((const char*)Ws + row*256 + (kb ^ ((row&7)<<4)));
        }
        #pragma unroll
        for (int fj=0;fj<2;fj++){
            int nr = nl0 + fj*16 + lr;
            x[fj] = *(const bf16x8*)((const char*)Xs + nr*256 + (kb ^ ((nr&7)<<4)));
        }
        #pragma unroll
        for (int fi=0;fi<4;fi++)
            #pragma unroll
            for (int fj=0;fj<2;fj++)
                acc[fi][fj] = __builtin_amdgcn_mfma_f32_16x16x32_bf16(a[fi], x[fj], acc[fi][fj], 0,0,0);
    }
    #pragma unroll
    for (int fi=0;fi<4;fi++){
        #pragma unroll
        for (int fj=0;fj<2;fj++){
            int o = o0 + fi*16 + lg*4;
            int n = n0 + nl0 + fj*16 + lr;
            float v0 = gelu(acc[fi][fj].x*s_sc[o+0] + s_sh[o+0]);
            float v1 = gelu(acc[fi][fj].y*s_sc[o+1] + s_sh[o+1]);
            float v2 = gelu(acc[fi][fj].z*s_sc[o+2] + s_sh[o+2]);
            float v3 = gelu(acc[fi][fj].w*s_sc[o+3] + s_sh[o+3]);
            ushort4 u; u.x=f2bf(v0); u.y=f2bf(v1); u.z=f2bf(v2); u.w=f2bf(v3);
            *(ushort4*)(h2 + (size_t)(b*NN + n)*C2 + jh*128 + o) = u;
        }
    }
}

// ---------------- K5: out = fmid + m_w2 @ h2 MFMA (K=256, chunked W) --------
__global__ __launch_bounds__(256) void k_out(
    const unsigned short* __restrict__ h2,
    const float* __restrict__ fmid,
    const float* __restrict__ w2g,
    float* __restrict__ out)
{
    __shared__ alignas(16) unsigned short Xs[64*256];   // [n][c2], 512B rows
    __shared__ alignas(16) unsigned short Wc[128*64];   // [o][c'], 128B rows
    const int tid = threadIdx.x;
    const int b  = blockIdx.x >> 7;
    const int n0 = (blockIdx.x & 127) * 64;

    #pragma unroll
    for (int p=0;p<8;p++){
        int n = (tid>>5) + p*8;
        int c8 = (tid&31)*8;
        uint4 v = *(const uint4*)(h2 + (size_t)(b*NN + n0 + n)*C2 + c8);
        int off = n*512 + ((c8*2) ^ ((n&7)<<4));
        *(uint4*)((char*)Xs + off) = v;
    }

    const int wid = tid >> 6, lane = tid & 63;
    const int lr = lane & 15, lg = lane >> 4;
    const int o0 = (wid >> 1) * 64;
    const int nl0 = (wid & 1) * 32;

    f32x4 acc[4][2];
    #pragma unroll
    for (int fi=0;fi<4;fi++){ acc[fi][0]=(f32x4){0,0,0,0}; acc[fi][1]=(f32x4){0,0,0,0}; }

    for (int kc=0; kc<4; ++kc){
        __syncthreads();   // Xs staged (kc=0) / prev compute done
        #pragma unroll 4
        for (int p=0;p<8;p++){
            int o = (tid>>4) + p*16;
            int c4 = (tid&15)*4;
            float4 w = *(const float4*)(w2g + (size_t)o*C2 + kc*64 + c4);
            int off = o*128 + ((c4*2) ^ ((o&7)<<4));
            uint2 v; v.x=pk2(w.x,w.y); v.y=pk2(w.z,w.w);
            *(uint2*)((char*)Wc + off) = v;
        }
        __syncthreads();
        #pragma unroll
        for (int kk=0; kk<2; ++kk){
            const int kbW = kk*64 + lg*16;
            const int kbX = kc*128 + kk*64 + lg*16;
            bf16x8 a[4], x[2];
            #pragma unroll
            for (int fi=0;fi<4;fi++){
                int row = o0 + fi*16 + lr;
                a[fi] = *(const bf16x8*)((const char*)Wc + row*128 + (kbW ^ ((row&7)<<4)));
            }
            #pragma unroll
            for (int fj=0;fj<2;fj++){
                int nr = nl0 + fj*16 + lr;
                x[fj] = *(const bf16x8*)((const char*)Xs + nr*512 + (kbX ^ ((nr&7)<<4)));
            }
            #pragma unroll
            for (int fi=0;fi<4;fi++)
                #pragma unroll
                for (int fj=0;fj<2;fj++)
                    acc[fi][fj] = __builtin_amdgcn_mfma_f32_16x16x32_bf16(a[fi], x[fj], acc[fi][fj], 0,0,0);
        }
    }
    #pragma unroll
    for (int fi=0;fi<4;fi++){
        #pragma unroll
        for (int fj=0;fj<2;fj++){
            int o = o0 + fi*16 + lg*4;
            int n = n0 + nl0 + fj*16 + lr;
            const float* fp = fmid + ((size_t)b*CC + o)*NN + n;
            float*       op = out  + ((size_t)b*CC + o)*NN + n;
            op[0*(size_t)NN] = fp[0*(size_t)NN] + acc[fi][fj].x;
            op[1*(size_t)NN] = fp[1*(size_t)NN] + acc[fi][fj].y;
            op[2*(size_t)NN] = fp[2*(size_t)NN] + acc[fi][fj].z;
            op[3*(size_t)NN] = fp[3*(size_t)NN] + acc[fi][fj].w;
        }
    }
}

extern "C" void kernel_launch(void* const* d_in, const int* in_sizes, int n_in,
                              void* d_out, int out_size, void* d_ws, size_t ws_size,
                              hipStream_t stream)
{
    const float* f      = (const float*)d_in[0];
    const float* dp     = (const float*)d_in[1];
    const int*   qidx   = (const int*)  d_in[2];
    const float* dirs   = (const float*)d_in[3];
    const float* de_w1  = (const float*)d_in[4];
    const float* de_bng = (const float*)d_in[5];
    const float* de_bnb = (const float*)d_in[6];
    const float* de_bnm = (const float*)d_in[7];
    const float* de_bnv = (const float*)d_in[8];
    const float* de_w2  = (const float*)d_in[9];
    const float* de_b2  = (const float*)d_in[10];
    const float* l_w1   = (const float*)d_in[11];
    const float* l_b1   = (const float*)d_in[12];
    const float* l_w2   = (const float*)d_in[13];
    const float* l_b2   = (const float*)d_in[14];
    const float* l_w3   = (const float*)d_in[15];
    const float* l_b3   = (const float*)d_in[16];
    const float* l_bng  = (const float*)d_in[17];
    const float* l_bnb  = (const float*)d_in[18];
    const float* l_bnm  = (const float*)d_in[19];
    const float* l_bnv  = (const float*)d_in[20];
    const float* m_w1   = (const float*)d_in[21];
    const float* m_bng  = (const float*)d_in[22];
    const float* m_bnb  = (const float*)d_in[23];
    const float* m_bnm  = (const float*)d_in[24];
    const float* m_bnv  = (const float*)d_in[25];
    const float* m_w2   = (const float*)d_in[26];

    char* ws = (char*)d_ws;
    // layout (bytes):
    //   g12   bf16(B,N,256): [0,        16777216)
    //   h2    bf16(B,N,256): [0,        16777216)  (aliases g12, dead after k_gather)
    //   pe    bf16(B,N,128): [16777216, 25165824)
    //   f3t   bf16(B,N,128): [25165824, 33554432)
    //   fmid  f32 (B,128,N): [33554432, 50331648)
    //   fmidb bf16(B,N,128): [50331648, 58720256)
    unsigned short* g12   = (unsigned short*)(ws + 0);
    unsigned short* h2    = (unsigned short*)(ws + 0);
    unsigned short* pe    = (unsigned short*)(ws + 16777216);
    unsigned short* f3t   = (unsigned short*)(ws + 25165824);
    float*          fmid  = (float*)(ws + 33554432);
    unsigned short* fmidb = (unsigned short*)(ws + 50331648);

    k_pe<<<dim3(512,2), dim3(64), 0, stream>>>(dp, dirs, de_w1, de_bng, de_bnb, de_bnm, de_bnv,
                                               de_w2, de_b2, pe);
    k_lin3<<<dim3(512), dim3(256), 0, stream>>>(f, l_w1, l_b1, l_w2, l_b2, l_w3, l_b3, g12, f3t);
    k_gather<<<dim3(8192), dim3(256), 0, stream>>>(f, qidx, g12, f3t, pe,
                                                   l_bng, l_bnb, l_bnm, l_bnv, fmid, fmidb);
    k_h2<<<dim3(512,2), dim3(256), 0, stream>>>(fmidb, m_w1, m_bng, m_bnb, m_bnm, m_bnv, h2);
    k_out<<<dim3(512), dim3(256), 0, stream>>>(h2, fmid, m_w2, (float*)d_out);
}

// Round 3
// 140.085 us; speedup vs baseline: 4.7074x; 1.2537x over previous
//
#include <hip/hip_runtime.h>
#include <hip/hip_bf16.h>
#include <cstdint>
#include <cstddef>

#define BB 4
#define CC 128
#define NN 8192
#define KK 16
#define HH 64
#define MM 32
#define C2 256

typedef __attribute__((ext_vector_type(8))) short bf16x8;
typedef __attribute__((ext_vector_type(4))) float f32x4;

__device__ __forceinline__ unsigned short f2bf(float f){
    unsigned int x = __float_as_uint(f);
    x += 0x7fffu + ((x >> 16) & 1u);
    return (unsigned short)(x >> 16);
}
__device__ __forceinline__ unsigned int pk2(float a, float b){
    return (unsigned int)f2bf(a) | ((unsigned int)f2bf(b) << 16);
}
__device__ __forceinline__ float lo16(unsigned int u){ return __uint_as_float(u << 16); }
__device__ __forceinline__ float hi16(unsigned int u){ return __uint_as_float(u & 0xffff0000u); }
__device__ __forceinline__ float b2f(unsigned short u){ return __uint_as_float((unsigned int)u << 16); }
__device__ __forceinline__ float gelu(float a){
    return 0.5f*a*(1.0f+erff(a*0.7071067811865475f));
}
// batch-affinity XCD remap: XCD pair {2b,2b+1} owns batch b.
// total blocks = 4*T (T even); returns batch b and tile in [0,T)
__device__ __forceinline__ void xcd_remap(int bid, int& b, int& tile){
    int xcd = bid & 7;
    b = xcd >> 1;
    tile = (bid >> 3) * 2 + (xcd & 1);
}

// ---------------- K1: pe = de_w2 @ gelu(bn(de_w1 @ theta_max)) + de_b2 ------
__global__ __launch_bounds__(64) void k_pe(
    const float* __restrict__ dp, const float* __restrict__ dirs,
    const float* __restrict__ w1,
    const float* __restrict__ bng, const float* __restrict__ bnb,
    const float* __restrict__ bnm, const float* __restrict__ bnv,
    const float* __restrict__ w2, const float* __restrict__ b2,
    unsigned short* __restrict__ pe)
{
    __shared__ float s_dir[MM*3];
    __shared__ float s_w1[HH*MM];
    __shared__ float s_w2[64*HH];
    __shared__ float s_sc[HH], s_sh[HH];
    __shared__ float s_b2[64];
    const int tid = threadIdx.x;
    const int jh = blockIdx.y;
    if (tid < MM){
        float x=dirs[tid*3+0], y=dirs[tid*3+1], z=dirs[tid*3+2];
        float inv = 1.0f / fmaxf(sqrtf(x*x+y*y+z*z), 1e-12f);
        s_dir[tid*3+0]=x*inv; s_dir[tid*3+1]=y*inv; s_dir[tid*3+2]=z*inv;
    }
    for (int i=tid;i<HH*MM;i+=64) s_w1[i]=w1[i];
    for (int i=tid;i<64*HH;i+=64) s_w2[i]=w2[(size_t)jh*64*HH + i];
    if (tid < HH){
        float sc = bng[tid] / sqrtf(bnv[tid] + 1e-5f);
        s_sc[tid]=sc; s_sh[tid]=bnb[tid]-bnm[tid]*sc;
    }
    if (tid < 64) s_b2[tid]=b2[jh*64+tid];
    __syncthreads();

    const int p = blockIdx.x*64 + tid;
    const int b = p >> 13, n = p & (NN-1);
    const float* base = dp + ((size_t)b*3*NN + n)*KK;
    float nx[KK], ny[KK], nz[KK];
    #pragma unroll
    for (int k=0;k<KK;k++){
        float x = base[k];
        float y = base[(size_t)NN*KK + k];
        float z = base[2*(size_t)NN*KK + k];
        float inv = 1.0f / fmaxf(sqrtf(x*x+y*y+z*z), 1e-12f);
        nx[k]=x*inv; ny[k]=y*inv; nz[k]=z*inv;
    }
    float tmax[MM];
    #pragma unroll
    for (int m=0;m<MM;m++){
        float vx=s_dir[m*3], vy=s_dir[m*3+1], vz=s_dir[m*3+2];
        float t = -1e30f;
        #pragma unroll
        for (int k=0;k<KK;k++)
            t = fmaxf(t, vx*nx[k]+vy*ny[k]+vz*nz[k]);
        tmax[m]=t;
    }
    float h[HH];
    #pragma unroll
    for (int j=0;j<HH;j++){
        const float4* wr = (const float4*)(s_w1 + j*MM);
        float a0=0.f,a1=0.f,a2=0.f,a3=0.f;
        #pragma unroll
        for (int q=0;q<MM/4;q++){
            float4 w = wr[q];
            a0 += w.x*tmax[4*q+0]; a1 += w.y*tmax[4*q+1];
            a2 += w.z*tmax[4*q+2]; a3 += w.w*tmax[4*q+3];
        }
        float a = (a0+a1)+(a2+a3);
        a = a*s_sc[j] + s_sh[j];
        h[j] = gelu(a);
    }
    unsigned short* outp = pe + (size_t)p*CC + jh*64;
    #pragma unroll 4
    for (int c=0;c<64;c+=4){
        float r[4];
        #pragma unroll
        for (int i=0;i<4;i++){
            const float4* wr = (const float4*)(s_w2 + (c+i)*HH);
            float a0=0.f,a1=0.f,a2=0.f,a3=0.f;
            #pragma unroll
            for (int q=0;q<HH/4;q++){
                float4 w = wr[q];
                a0 += w.x*h[4*q+0]; a1 += w.y*h[4*q+1];
                a2 += w.z*h[4*q+2]; a3 += w.w*h[4*q+3];
            }
            r[i] = (a0+a1)+(a2+a3) + s_b2[c+i];
        }
        ushort4 u; u.x=f2bf(r[0]); u.y=f2bf(r[1]); u.z=f2bf(r[2]); u.w=f2bf(r[3]);
        *(ushort4*)(outp + c) = u;
    }
}

// ---------------- K2: f1/f2/f3 MFMA GEMM ------------------------------------
__global__ __launch_bounds__(256) void k_lin3(
    const float* __restrict__ f,
    const float* __restrict__ w1g, const float* __restrict__ b1g,
    const float* __restrict__ w2g, const float* __restrict__ b2g,
    const float* __restrict__ w3g, const float* __restrict__ b3g,
    unsigned short* __restrict__ g12, unsigned short* __restrict__ f3t)
{
    __shared__ alignas(16) unsigned short Xs[64*128];
    __shared__ alignas(16) unsigned short Ws[128*128];
    __shared__ float s_bias[128];
    const int tid = threadIdx.x;
    int b, tile;
    xcd_remap(blockIdx.x, b, tile);   // 128 tiles per batch
    const int n0 = tile * 64;

    {
        const int j = (tid & 15) * 4;
        #pragma unroll
        for (int p = 0; p < 2; ++p){
            const int cb = ((tid >> 4) + p*16) * 4;
            const float* src = f + ((size_t)b*CC + cb)*NN + n0 + j;
            float4 r0 = *(const float4*)(src);
            float4 r1 = *(const float4*)(src + NN);
            float4 r2 = *(const float4*)(src + 2*(size_t)NN);
            float4 r3 = *(const float4*)(src + 3*(size_t)NN);
            const float rr[4][4] = {{r0.x,r1.x,r2.x,r3.x},{r0.y,r1.y,r2.y,r3.y},
                                    {r0.z,r1.z,r2.z,r3.z},{r0.w,r1.w,r2.w,r3.w}};
            #pragma unroll
            for (int i=0;i<4;i++){
                int n = j + i;
                int off = n*256 + ((cb*2) ^ ((n&7)<<4));
                uint2 v; v.x = pk2(rr[i][0], rr[i][1]); v.y = pk2(rr[i][2], rr[i][3]);
                *(uint2*)((char*)Xs + off) = v;
            }
        }
    }

    const int wid = tid >> 6, lane = tid & 63;
    const int lr = lane & 15, lg = lane >> 4;
    const int o0 = (wid >> 1) * 64;
    const int nl0 = (wid & 1) * 32;

    for (int mat = 0; mat < 3; ++mat){
        const float* Wg = (mat==0)? w1g : (mat==1)? w2g : w3g;
        const float* Bg = (mat==0)? b1g : (mat==1)? b2g : b3g;
        __syncthreads();
        #pragma unroll 4
        for (int p = 0; p < 16; ++p){
            int o = (tid >> 5) + p*8;
            int c4 = (tid & 31) * 4;
            float4 w = *(const float4*)(Wg + (size_t)o*CC + c4);
            int off = o*256 + ((c4*2) ^ ((o&7)<<4));
            uint2 v; v.x = pk2(w.x, w.y); v.y = pk2(w.z, w.w);
            *(uint2*)((char*)Ws + off) = v;
        }
        if (tid < 128) s_bias[tid] = Bg[tid];
        __syncthreads();

        f32x4 acc[4][2];
        #pragma unroll
        for (int fi=0;fi<4;fi++){
            int o = o0 + fi*16 + lg*4;
            f32x4 bi = {s_bias[o], s_bias[o+1], s_bias[o+2], s_bias[o+3]};
            acc[fi][0] = bi; acc[fi][1] = bi;
        }
        #pragma unroll
        for (int kk=0; kk<4; ++kk){
            const int kb = kk*64 + lg*16;
            bf16x8 a[4], x[2];
            #pragma unroll
            for (int fi=0;fi<4;fi++){
                int row = o0 + fi*16 + lr;
                a[fi] = *(const bf16x8*)((const char*)Ws + row*256 + (kb ^ ((row&7)<<4)));
            }
            #pragma unroll
            for (int fj=0;fj<2;fj++){
                int nr = nl0 + fj*16 + lr;
                x[fj] = *(const bf16x8*)((const char*)Xs + nr*256 + (kb ^ ((nr&7)<<4)));
            }
            #pragma unroll
            for (int fi=0;fi<4;fi++)
                #pragma unroll
                for (int fj=0;fj<2;fj++)
                    acc[fi][fj] = __builtin_amdgcn_mfma_f32_16x16x32_bf16(a[fi], x[fj], acc[fi][fj], 0,0,0);
        }
        #pragma unroll
        for (int fi=0;fi<4;fi++){
            #pragma unroll
            for (int fj=0;fj<2;fj++){
                int o = o0 + fi*16 + lg*4;
                int n = n0 + nl0 + fj*16 + lr;
                ushort4 u;
                u.x = f2bf(acc[fi][fj].x); u.y = f2bf(acc[fi][fj].y);
                u.z = f2bf(acc[fi][fj].z); u.w = f2bf(acc[fi][fj].w);
                if (mat == 2)
                    *(ushort4*)(f3t + (size_t)(b*NN + n)*CC + o) = u;
                else
                    *(ushort4*)(g12 + (size_t)(b*NN + n)*C2 + mat*CC + o) = u;
            }
        }
    }
}

// ---------------- K3: knn gather-max + combine + BN + residual --------------
__global__ __launch_bounds__(256) void k_gather(
    const float* __restrict__ f,
    const int* __restrict__ qidx,
    const unsigned short* __restrict__ g12,
    const unsigned short* __restrict__ f3t,
    const unsigned short* __restrict__ pe,
    const float* __restrict__ bn_g, const float* __restrict__ bn_b,
    const float* __restrict__ bn_m, const float* __restrict__ bn_v,
    unsigned short* __restrict__ fmidb)
{
    const int lane = threadIdx.x & 63;
    const int wrp  = threadIdx.x >> 6;
    int b, tile;
    xcd_remap(blockIdx.x, b, tile);   // 2048 tiles (of 4 points) per batch
    const int n = tile*4 + wrp;
    const int p = b*NN + n;
    const int* idxp = qidx + (size_t)p*KK;

    uint2 sv = *(const uint2*)(g12 + (size_t)p*C2 + lane*4);
    float s0 = lo16(sv.x), s1 = hi16(sv.x), s2 = lo16(sv.y), s3 = hi16(sv.y);

    float a0=-3.0e38f, a1=-3.0e38f, a2=-3.0e38f, a3=-3.0e38f;
    const unsigned short* gb = g12 + (size_t)b*NN*C2 + lane*4;
    #pragma unroll
    for (int k=0;k<KK;k++){
        int j = idxp[k];
        uint2 gv = *(const uint2*)(gb + (size_t)j*C2);
        a0 = fmaxf(a0, lo16(gv.x)); a1 = fmaxf(a1, hi16(gv.x));
        a2 = fmaxf(a2, lo16(gv.y)); a3 = fmaxf(a3, hi16(gv.y));
    }
    if (lane >= 32){ a0 += s0; a1 += s1; a2 += s2; a3 += s3; }
    float c0v = a0 + __shfl_xor(a0, 32);
    float c1v = a1 + __shfl_xor(a1, 32);
    float c2v = a2 + __shfl_xor(a2, 32);
    float c3v = a3 + __shfl_xor(a3, 32);
    if (lane < 32){
        const int ch = lane*4;
        uint2 f3v = *(const uint2*)(f3t + (size_t)p*CC + ch);
        uint2 pev = *(const uint2*)(pe  + (size_t)p*CC + ch);
        float s[4] = { c0v + lo16(f3v.x), c1v + hi16(f3v.x),
                       c2v + lo16(f3v.y), c3v + hi16(f3v.y) };
        float pv[4] = { lo16(pev.x), hi16(pev.x), lo16(pev.y), hi16(pev.y) };
        float4 g4 = *(const float4*)(bn_g + ch);
        float4 b4 = *(const float4*)(bn_b + ch);
        float4 m4 = *(const float4*)(bn_m + ch);
        float4 v4 = *(const float4*)(bn_v + ch);
        const float gg[4]={g4.x,g4.y,g4.z,g4.w}, bbv[4]={b4.x,b4.y,b4.z,b4.w},
                    mmv[4]={m4.x,m4.y,m4.z,m4.w}, vvv[4]={v4.x,v4.y,v4.z,v4.w};
        const float* fc = f + ((size_t)b*CC + ch)*NN + n;
        float ov[4];
        #pragma unroll
        for (int i=0;i<4;i++){
            float sc = gg[i] / sqrtf(vvv[i] + 1e-5f);
            float bnval = (s[i]-mmv[i])*sc + bbv[i];
            ov[i] = fc[(size_t)i*NN] + bnval + pv[i];
        }
        ushort4 u; u.x=f2bf(ov[0]); u.y=f2bf(ov[1]); u.z=f2bf(ov[2]); u.w=f2bf(ov[3]);
        *(ushort4*)(fmidb + (size_t)p*CC + ch) = u;
    }
}

// ---------------- K4: h2 = gelu(bn(m_w1 @ fmid)) MFMA -----------------------
__global__ __launch_bounds__(256) void k_h2(
    const unsigned short* __restrict__ fmidb,
    const float* __restrict__ w1g,
    const float* __restrict__ bng, const float* __restrict__ bnb,
    const float* __restrict__ bnm, const float* __restrict__ bnv,
    unsigned short* __restrict__ h2)
{
    __shared__ alignas(16) unsigned short Xs[64*128];
    __shared__ alignas(16) unsigned short Ws[128*128];
    __shared__ float s_sc[128], s_sh[128];
    const int tid = threadIdx.x;
    int b, tile;
    xcd_remap(blockIdx.x, b, tile);
    const int n0 = tile * 64;
    const int jh = blockIdx.y;

    #pragma unroll
    for (int p=0;p<4;p++){
        int n = (tid>>4) + p*16;
        int c8 = (tid&15)*8;
        uint4 v = *(const uint4*)(fmidb + (size_t)(b*NN + n0 + n)*CC + c8);
        int off = n*256 + ((c8*2) ^ ((n&7)<<4));
        *(uint4*)((char*)Xs + off) = v;
    }
    const float* Wg = w1g + (size_t)jh*128*CC;
    #pragma unroll 4
    for (int p = 0; p < 16; ++p){
        int o = (tid >> 5) + p*8;
        int c4 = (tid & 31) * 4;
        float4 w = *(const float4*)(Wg + (size_t)o*CC + c4);
        int off = o*256 + ((c4*2) ^ ((o&7)<<4));
        uint2 v; v.x = pk2(w.x, w.y); v.y = pk2(w.z, w.w);
        *(uint2*)((char*)Ws + off) = v;
    }
    if (tid < 128){
        int jg = jh*128 + tid;
        float sc = bng[jg] / sqrtf(bnv[jg] + 1e-5f);
        s_sc[tid] = sc; s_sh[tid] = bnb[jg] - bnm[jg]*sc;
    }
    __syncthreads();

    const int wid = tid >> 6, lane = tid & 63;
    const int lr = lane & 15, lg = lane >> 4;
    const int o0 = (wid >> 1) * 64;
    const int nl0 = (wid & 1) * 32;

    f32x4 acc[4][2];
    #pragma unroll
    for (int fi=0;fi<4;fi++){ acc[fi][0]=(f32x4){0,0,0,0}; acc[fi][1]=(f32x4){0,0,0,0}; }
    #pragma unroll
    for (int kk=0; kk<4; ++kk){
        const int kb = kk*64 + lg*16;
        bf16x8 a[4], x[2];
        #pragma unroll
        for (int fi=0;fi<4;fi++){
            int row = o0 + fi*16 + lr;
            a[fi] = *(const bf16x8*)((const char*)Ws + row*256 + (kb ^ ((row&7)<<4)));
        }
        #pragma unroll
        for (int fj=0;fj<2;fj++){
            int nr = nl0 + fj*16 + lr;
            x[fj] = *(const bf16x8*)((const char*)Xs + nr*256 + (kb ^ ((nr&7)<<4)));
        }
        #pragma unroll
        for (int fi=0;fi<4;fi++)
            #pragma unroll
            for (int fj=0;fj<2;fj++)
                acc[fi][fj] = __builtin_amdgcn_mfma_f32_16x16x32_bf16(a[fi], x[fj], acc[fi][fj], 0,0,0);
    }
    #pragma unroll
    for (int fi=0;fi<4;fi++){
        #pragma unroll
        for (int fj=0;fj<2;fj++){
            int o = o0 + fi*16 + lg*4;
            int n = n0 + nl0 + fj*16 + lr;
            float v0 = gelu(acc[fi][fj].x*s_sc[o+0] + s_sh[o+0]);
            float v1 = gelu(acc[fi][fj].y*s_sc[o+1] + s_sh[o+1]);
            float v2 = gelu(acc[fi][fj].z*s_sc[o+2] + s_sh[o+2]);
            float v3 = gelu(acc[fi][fj].w*s_sc[o+3] + s_sh[o+3]);
            ushort4 u; u.x=f2bf(v0); u.y=f2bf(v1); u.z=f2bf(v2); u.w=f2bf(v3);
            *(ushort4*)(h2 + (size_t)(b*NN + n)*C2 + jh*128 + o) = u;
        }
    }
}

// ---------------- K5: out = fmid + m_w2 @ h2 MFMA (K=256, chunked W) --------
__global__ __launch_bounds__(256) void k_out(
    const unsigned short* __restrict__ h2,
    const unsigned short* __restrict__ fmidb,
    const float* __restrict__ w2g,
    float* __restrict__ out)
{
    __shared__ alignas(16) unsigned short Xs[64*256];
    __shared__ alignas(16) unsigned short Wc[128*64];
    const int tid = threadIdx.x;
    int b, tile;
    xcd_remap(blockIdx.x, b, tile);
    const int n0 = tile * 64;

    #pragma unroll
    for (int p=0;p<8;p++){
        int n = (tid>>5) + p*8;
        int c8 = (tid&31)*8;
        uint4 v = *(const uint4*)(h2 + (size_t)(b*NN + n0 + n)*C2 + c8);
        int off = n*512 + ((c8*2) ^ ((n&7)<<4));
        *(uint4*)((char*)Xs + off) = v;
    }

    const int wid = tid >> 6, lane = tid & 63;
    const int lr = lane & 15, lg = lane >> 4;
    const int o0 = (wid >> 1) * 64;
    const int nl0 = (wid & 1) * 32;

    f32x4 acc[4][2];
    #pragma unroll
    for (int fi=0;fi<4;fi++){ acc[fi][0]=(f32x4){0,0,0,0}; acc[fi][1]=(f32x4){0,0,0,0}; }

    for (int kc=0; kc<4; ++kc){
        __syncthreads();
        #pragma unroll 4
        for (int p=0;p<8;p++){
            int o = (tid>>4) + p*16;
            int c4 = (tid&15)*4;
            float4 w = *(const float4*)(w2g + (size_t)o*C2 + kc*64 + c4);
            int off = o*128 + ((c4*2) ^ ((o&7)<<4));
            uint2 v; v.x=pk2(w.x,w.y); v.y=pk2(w.z,w.w);
            *(uint2*)((char*)Wc + off) = v;
        }
        __syncthreads();
        #pragma unroll
        for (int kk=0; kk<2; ++kk){
            const int kbW = kk*64 + lg*16;
            const int kbX = kc*128 + kk*64 + lg*16;
            bf16x8 a[4], x[2];
            #pragma unroll
            for (int fi=0;fi<4;fi++){
                int row = o0 + fi*16 + lr;
                a[fi] = *(const bf16x8*)((const char*)Wc + row*128 + (kbW ^ ((row&7)<<4)));
            }
            #pragma unroll
            for (int fj=0;fj<2;fj++){
                int nr = nl0 + fj*16 + lr;
                x[fj] = *(const bf16x8*)((const char*)Xs + nr*512 + (kbX ^ ((nr&7)<<4)));
            }
            #pragma unroll
            for (int fi=0;fi<4;fi++)
                #pragma unroll
                for (int fj=0;fj<2;fj++)
                    acc[fi][fj] = __builtin_amdgcn_mfma_f32_16x16x32_bf16(a[fi], x[fj], acc[fi][fj], 0,0,0);
        }
    }
    #pragma unroll
    for (int fi=0;fi<4;fi++){
        #pragma unroll
        for (int fj=0;fj<2;fj++){
            int o = o0 + fi*16 + lg*4;
            int n = n0 + nl0 + fj*16 + lr;
            ushort4 r4 = *(const ushort4*)(fmidb + (size_t)(b*NN + n)*CC + o);
            float* op = out + ((size_t)b*CC + o)*NN + n;
            op[0*(size_t)NN] = b2f(r4.x) + acc[fi][fj].x;
            op[1*(size_t)NN] = b2f(r4.y) + acc[fi][fj].y;
            op[2*(size_t)NN] = b2f(r4.z) + acc[fi][fj].z;
            op[3*(size_t)NN] = b2f(r4.w) + acc[fi][fj].w;
        }
    }
}

extern "C" void kernel_launch(void* const* d_in, const int* in_sizes, int n_in,
                              void* d_out, int out_size, void* d_ws, size_t ws_size,
                              hipStream_t stream)
{
    const float* f      = (const float*)d_in[0];
    const float* dp     = (const float*)d_in[1];
    const int*   qidx   = (const int*)  d_in[2];
    const float* dirs   = (const float*)d_in[3];
    const float* de_w1  = (const float*)d_in[4];
    const float* de_bng = (const float*)d_in[5];
    const float* de_bnb = (const float*)d_in[6];
    const float* de_bnm = (const float*)d_in[7];
    const float* de_bnv = (const float*)d_in[8];
    const float* de_w2  = (const float*)d_in[9];
    const float* de_b2  = (const float*)d_in[10];
    const float* l_w1   = (const float*)d_in[11];
    const float* l_b1   = (const float*)d_in[12];
    const float* l_w2   = (const float*)d_in[13];
    const float* l_b2   = (const float*)d_in[14];
    const float* l_w3   = (const float*)d_in[15];
    const float* l_b3   = (const float*)d_in[16];
    const float* l_bng  = (const float*)d_in[17];
    const float* l_bnb  = (const float*)d_in[18];
    const float* l_bnm  = (const float*)d_in[19];
    const float* l_bnv  = (const float*)d_in[20];
    const float* m_w1   = (const float*)d_in[21];
    const float* m_bng  = (const float*)d_in[22];
    const float* m_bnb  = (const float*)d_in[23];
    const float* m_bnm  = (const float*)d_in[24];
    const float* m_bnv  = (const float*)d_in[25];
    const float* m_w2   = (const float*)d_in[26];

    char* ws = (char*)d_ws;
    // layout (bytes):
    //   g12   bf16(B,N,256): [0,        16777216)
    //   h2    bf16(B,N,256): [0,        16777216)  (aliases g12, dead after k_gather)
    //   pe    bf16(B,N,128): [16777216, 25165824)
    //   f3t   bf16(B,N,128): [25165824, 33554432)
    //   fmidb bf16(B,N,128): [33554432, 41943040)
    unsigned short* g12   = (unsigned short*)(ws + 0);
    unsigned short* h2    = (unsigned short*)(ws + 0);
    unsigned short* pe    = (unsigned short*)(ws + 16777216);
    unsigned short* f3t   = (unsigned short*)(ws + 25165824);
    unsigned short* fmidb = (unsigned short*)(ws + 33554432);

    k_pe<<<dim3(512,2), dim3(64), 0, stream>>>(dp, dirs, de_w1, de_bng, de_bnb, de_bnm, de_bnv,
                                               de_w2, de_b2, pe);
    k_lin3<<<dim3(512), dim3(256), 0, stream>>>(f, l_w1, l_b1, l_w2, l_b2, l_w3, l_b3, g12, f3t);
    k_gather<<<dim3(8192), dim3(256), 0, stream>>>(f, qidx, g12, f3t, pe,
                                                   l_bng, l_bnb, l_bnm, l_bnv, fmidb);
    k_h2<<<dim3(512,2), dim3(256), 0, stream>>>(fmidb, m_w1, m_bng, m_bnb, m_bnm, m_bnv, h2);
    k_out<<<dim3(512), dim3(256), 0, stream>>>(h2, fmidb, m_w2, (float*)d_out);
}

// Round 4
// 102.632 us; speedup vs baseline: 6.4252x; 1.3649x over previous
//
#include <hip/hip_runtime.h>
#include <hip/hip_bf16.h>
#include <cstdint>
#include <cstddef>

#define BB 4
#define CC 128
#define NN 8192
#define KK 16
#define HH 64
#define MM 32
#define C2 256

typedef __attribute__((ext_vector_type(8))) short bf16x8;
typedef __attribute__((ext_vector_type(4))) float f32x4;

__device__ __forceinline__ unsigned short f2bf(float f){
    unsigned int x = __float_as_uint(f);
    x += 0x7fffu + ((x >> 16) & 1u);
    return (unsigned short)(x >> 16);
}
__device__ __forceinline__ unsigned int pk2(float a, float b){
    return (unsigned int)f2bf(a) | ((unsigned int)f2bf(b) << 16);
}
__device__ __forceinline__ float lo16(unsigned int u){ return __uint_as_float(u << 16); }
__device__ __forceinline__ float hi16(unsigned int u){ return __uint_as_float(u & 0xffff0000u); }
__device__ __forceinline__ float b2f(unsigned short u){ return __uint_as_float((unsigned int)u << 16); }
__device__ __forceinline__ float gelu(float a){
    return 0.5f*a*(1.0f+erff(a*0.7071067811865475f));
}
// batch-affinity XCD remap: XCD pair {2b,2b+1} owns batch b.
__device__ __forceinline__ void xcd_remap(int bid, int& b, int& tile){
    int xcd = bid & 7;
    b = xcd >> 1;
    tile = (bid >> 3) * 2 + (xcd & 1);
}

// ---------------- K1: pe path, fused MFMA version ---------------------------
// 256 thr / 4 waves per 64-point tile; grid 512 XCD-remapped.
__global__ __launch_bounds__(256) void k_pe(
    const float* __restrict__ dp, const float* __restrict__ dirs,
    const float* __restrict__ w1,
    const float* __restrict__ bng, const float* __restrict__ bnb,
    const float* __restrict__ bnm, const float* __restrict__ bnv,
    const float* __restrict__ w2, const float* __restrict__ b2,
    unsigned short* __restrict__ pe)
{
    __shared__ float s_dx[MM], s_dy[MM], s_dz[MM];
    __shared__ alignas(16) float dnx[64*16], dny[64*16], dnz[64*16]; // [np][k], 64B rows, ^((np&3)<<4)
    __shared__ alignas(16) unsigned short th[64*32];   // [np][dir] bf16, ^((np&3)<<4)
    __shared__ alignas(16) unsigned short ws1[64*32];  // [h][dir] bf16, ^((row&3)<<4)
    __shared__ alignas(16) unsigned short hs[64*64];   // [pt][h] bf16, ^((pt&7)<<4)
    __shared__ alignas(16) unsigned short ws2[128*64]; // [o][h] bf16, ^((row&7)<<4)
    __shared__ float s_sc[HH], s_sh[HH], s_b2[CC];

    const int tid = threadIdx.x;
    int b, tile; xcd_remap(blockIdx.x, b, tile);
    const int n0 = tile * 64;

    if (tid < MM){
        float x=dirs[tid*3+0], y=dirs[tid*3+1], z=dirs[tid*3+2];
        float inv = 1.0f / fmaxf(sqrtf(x*x+y*y+z*z), 1e-12f);
        s_dx[tid]=x*inv; s_dy[tid]=y*inv; s_dz[tid]=z*inv;
    }
    // ws1: 64x32 f32 -> bf16 (2048 floats = 512 float4, 2/thread)
    #pragma unroll
    for (int p=0;p<2;p++){
        int id = tid + p*256;
        int row = id >> 3, c4 = (id & 7)*4;
        float4 w = *(const float4*)(w1 + row*MM + c4);
        int off = row*64 + ((c4*2) ^ ((row&3)<<4));
        uint2 v; v.x = pk2(w.x,w.y); v.y = pk2(w.z,w.w);
        *(uint2*)((char*)ws1 + off) = v;
    }
    // ws2: 128x64 f32 -> bf16 (8192 floats = 2048 float4, 8/thread)
    #pragma unroll
    for (int p=0;p<8;p++){
        int id = tid + p*256;
        int row = id >> 4, c4 = (id & 15)*4;
        float4 w = *(const float4*)(w2 + row*HH + c4);
        int off = row*128 + ((c4*2) ^ ((row&7)<<4));
        uint2 v; v.x = pk2(w.x,w.y); v.y = pk2(w.z,w.w);
        *(uint2*)((char*)ws2 + off) = v;
    }
    if (tid < HH){
        float sc = bng[tid] / sqrtf(bnv[tid] + 1e-5f);
        s_sc[tid]=sc; s_sh[tid]=bnb[tid]-bnm[tid]*sc;
    }
    if (tid >= 64 && tid < 192) s_b2[tid-64] = b2[tid-64];

    // dp tile stage + normalize: comp c region is 4KB contiguous
    {
        const size_t cstride = (size_t)NN*KK;
        const float* base = dp + (size_t)b*3*cstride + (size_t)n0*KK + tid*4;
        float4 X = *(const float4*)(base);
        float4 Y = *(const float4*)(base + cstride);
        float4 Z = *(const float4*)(base + 2*cstride);
        float i0 = 1.0f/fmaxf(sqrtf(X.x*X.x+Y.x*Y.x+Z.x*Z.x),1e-12f);
        float i1 = 1.0f/fmaxf(sqrtf(X.y*X.y+Y.y*Y.y+Z.y*Z.y),1e-12f);
        float i2 = 1.0f/fmaxf(sqrtf(X.z*X.z+Y.z*Y.z+Z.z*Z.z),1e-12f);
        float i3 = 1.0f/fmaxf(sqrtf(X.w*X.w+Y.w*Y.w+Z.w*Z.w),1e-12f);
        float4 xn = {X.x*i0, X.y*i1, X.z*i2, X.w*i3};
        float4 yn = {Y.x*i0, Y.y*i1, Y.z*i2, Y.w*i3};
        float4 zn = {Z.x*i0, Z.y*i1, Z.z*i2, Z.w*i3};
        const int np = tid >> 2;
        const int off = np*64 + (((tid&3)*16) ^ ((np&3)<<4));
        *(float4*)((char*)dnx + off) = xn;
        *(float4*)((char*)dny + off) = yn;
        *(float4*)((char*)dnz + off) = zn;
    }
    __syncthreads();

    // Phase 1: theta_max for 8 dirs per thread
    {
        const int np = tid & 63, dg = tid >> 6;
        float vx[8], vy[8], vz[8];
        #pragma unroll
        for (int d=0;d<8;d++){ vx[d]=s_dx[dg*8+d]; vy[d]=s_dy[dg*8+d]; vz[d]=s_dz[dg*8+d]; }
        float tm[8];
        #pragma unroll
        for (int d=0;d<8;d++) tm[d] = -2.0f;
        #pragma unroll
        for (int g=0;g<4;g++){
            int off = np*64 + ((g*16) ^ ((np&3)<<4));
            float4 x4 = *(const float4*)((const char*)dnx + off);
            float4 y4 = *(const float4*)((const char*)dny + off);
            float4 z4 = *(const float4*)((const char*)dnz + off);
            const float xs[4]={x4.x,x4.y,x4.z,x4.w}, ys[4]={y4.x,y4.y,y4.z,y4.w},
                        zs[4]={z4.x,z4.y,z4.z,z4.w};
            #pragma unroll
            for (int q=0;q<4;q++)
                #pragma unroll
                for (int d=0;d<8;d++)
                    tm[d] = fmaxf(tm[d], vx[d]*xs[q]+vy[d]*ys[q]+vz[d]*zs[q]);
        }
        uint4 t4; t4.x=pk2(tm[0],tm[1]); t4.y=pk2(tm[2],tm[3]);
        t4.z=pk2(tm[4],tm[5]); t4.w=pk2(tm[6],tm[7]);
        int off = np*64 + ((dg*16) ^ ((np&3)<<4));
        *(uint4*)((char*)th + off) = t4;
    }
    __syncthreads();

    const int wid = tid >> 6, lane = tid & 63;
    const int lr = lane & 15, lg = lane >> 4;

    // GEMM1: h[64ch][64pt] = W1 @ theta ; K=32 (one MFMA k-step)
    {
        const int arow = wid*16 + lr;
        bf16x8 afr = *(const bf16x8*)((const char*)ws1 + arow*64 + ((lg*16) ^ ((arow&3)<<4)));
        f32x4 hacc[4];
        #pragma unroll
        for (int nf=0;nf<4;nf++){
            int pt = nf*16 + lr;
            bf16x8 bfr = *(const bf16x8*)((const char*)th + pt*64 + ((lg*16) ^ ((pt&3)<<4)));
            f32x4 z = {0.f,0.f,0.f,0.f};
            hacc[nf] = __builtin_amdgcn_mfma_f32_16x16x32_bf16(afr, bfr, z, 0,0,0);
        }
        // bn + gelu, write hs
        #pragma unroll
        for (int nf=0;nf<4;nf++){
            int ch0 = wid*16 + lg*4;
            int pt = nf*16 + lr;
            float g0 = gelu(hacc[nf].x*s_sc[ch0+0] + s_sh[ch0+0]);
            float g1 = gelu(hacc[nf].y*s_sc[ch0+1] + s_sh[ch0+1]);
            float g2 = gelu(hacc[nf].z*s_sc[ch0+2] + s_sh[ch0+2]);
            float g3 = gelu(hacc[nf].w*s_sc[ch0+3] + s_sh[ch0+3]);
            uint2 v; v.x = pk2(g0,g1); v.y = pk2(g2,g3);
            *(uint2*)((char*)hs + pt*128 + ((ch0*2) ^ ((pt&7)<<4))) = v;
        }
    }
    __syncthreads();

    // GEMM2: pe[128ch][64pt] = W2 @ h ; K=64 (2 k-steps); wave owns 2 m-frags
    {
        f32x4 pacc[2][4];
        #pragma unroll
        for (int mi=0;mi<2;mi++)
            #pragma unroll
            for (int nf=0;nf<4;nf++) pacc[mi][nf] = (f32x4){0.f,0.f,0.f,0.f};
        #pragma unroll
        for (int ks=0;ks<2;ks++){
            bf16x8 a[2], x[4];
            #pragma unroll
            for (int mi=0;mi<2;mi++){
                int row = (wid*2+mi)*16 + lr;
                a[mi] = *(const bf16x8*)((const char*)ws2 + row*128 + ((ks*64 + lg*16) ^ ((row&7)<<4)));
            }
            #pragma unroll
            for (int nf=0;nf<4;nf++){
                int pt = nf*16 + lr;
                x[nf] = *(const bf16x8*)((const char*)hs + pt*128 + ((ks*64 + lg*16) ^ ((pt&7)<<4)));
            }
            #pragma unroll
            for (int mi=0;mi<2;mi++)
                #pragma unroll
                for (int nf=0;nf<4;nf++)
                    pacc[mi][nf] = __builtin_amdgcn_mfma_f32_16x16x32_bf16(a[mi], x[nf], pacc[mi][nf], 0,0,0);
        }
        #pragma unroll
        for (int mi=0;mi<2;mi++){
            #pragma unroll
            for (int nf=0;nf<4;nf++){
                int ch0 = (wid*2+mi)*16 + lg*4;
                int pt = nf*16 + lr;
                ushort4 u;
                u.x = f2bf(pacc[mi][nf].x + s_b2[ch0+0]);
                u.y = f2bf(pacc[mi][nf].y + s_b2[ch0+1]);
                u.z = f2bf(pacc[mi][nf].z + s_b2[ch0+2]);
                u.w = f2bf(pacc[mi][nf].w + s_b2[ch0+3]);
                *(ushort4*)(pe + (size_t)(b*NN + n0 + pt)*CC + ch0) = u;
            }
        }
    }
}

// ---------------- K2: f1/f2/f3 MFMA GEMM ------------------------------------
__global__ __launch_bounds__(256) void k_lin3(
    const float* __restrict__ f,
    const float* __restrict__ w1g, const float* __restrict__ b1g,
    const float* __restrict__ w2g, const float* __restrict__ b2g,
    const float* __restrict__ w3g, const float* __restrict__ b3g,
    unsigned short* __restrict__ g12, unsigned short* __restrict__ f3t)
{
    __shared__ alignas(16) unsigned short Xs[64*128];
    __shared__ alignas(16) unsigned short Ws[128*128];
    __shared__ float s_bias[128];
    const int tid = threadIdx.x;
    int b, tile;
    xcd_remap(blockIdx.x, b, tile);   // 128 tiles per batch
    const int n0 = tile * 64;

    {
        const int j = (tid & 15) * 4;
        #pragma unroll
        for (int p = 0; p < 2; ++p){
            const int cb = ((tid >> 4) + p*16) * 4;
            const float* src = f + ((size_t)b*CC + cb)*NN + n0 + j;
            float4 r0 = *(const float4*)(src);
            float4 r1 = *(const float4*)(src + NN);
            float4 r2 = *(const float4*)(src + 2*(size_t)NN);
            float4 r3 = *(const float4*)(src + 3*(size_t)NN);
            const float rr[4][4] = {{r0.x,r1.x,r2.x,r3.x},{r0.y,r1.y,r2.y,r3.y},
                                    {r0.z,r1.z,r2.z,r3.z},{r0.w,r1.w,r2.w,r3.w}};
            #pragma unroll
            for (int i=0;i<4;i++){
                int n = j + i;
                int off = n*256 + ((cb*2) ^ ((n&7)<<4));
                uint2 v; v.x = pk2(rr[i][0], rr[i][1]); v.y = pk2(rr[i][2], rr[i][3]);
                *(uint2*)((char*)Xs + off) = v;
            }
        }
    }

    const int wid = tid >> 6, lane = tid & 63;
    const int lr = lane & 15, lg = lane >> 4;
    const int o0 = (wid >> 1) * 64;
    const int nl0 = (wid & 1) * 32;

    for (int mat = 0; mat < 3; ++mat){
        const float* Wg = (mat==0)? w1g : (mat==1)? w2g : w3g;
        const float* Bg = (mat==0)? b1g : (mat==1)? b2g : b3g;
        __syncthreads();
        #pragma unroll 4
        for (int p = 0; p < 16; ++p){
            int o = (tid >> 5) + p*8;
            int c4 = (tid & 31) * 4;
            float4 w = *(const float4*)(Wg + (size_t)o*CC + c4);
            int off = o*256 + ((c4*2) ^ ((o&7)<<4));
            uint2 v; v.x = pk2(w.x, w.y); v.y = pk2(w.z, w.w);
            *(uint2*)((char*)Ws + off) = v;
        }
        if (tid < 128) s_bias[tid] = Bg[tid];
        __syncthreads();

        f32x4 acc[4][2];
        #pragma unroll
        for (int fi=0;fi<4;fi++){
            int o = o0 + fi*16 + lg*4;
            f32x4 bi = {s_bias[o], s_bias[o+1], s_bias[o+2], s_bias[o+3]};
            acc[fi][0] = bi; acc[fi][1] = bi;
        }
        #pragma unroll
        for (int kk=0; kk<4; ++kk){
            const int kb = kk*64 + lg*16;
            bf16x8 a[4], x[2];
            #pragma unroll
            for (int fi=0;fi<4;fi++){
                int row = o0 + fi*16 + lr;
                a[fi] = *(const bf16x8*)((const char*)Ws + row*256 + (kb ^ ((row&7)<<4)));
            }
            #pragma unroll
            for (int fj=0;fj<2;fj++){
                int nr = nl0 + fj*16 + lr;
                x[fj] = *(const bf16x8*)((const char*)Xs + nr*256 + (kb ^ ((nr&7)<<4)));
            }
            #pragma unroll
            for (int fi=0;fi<4;fi++)
                #pragma unroll
                for (int fj=0;fj<2;fj++)
                    acc[fi][fj] = __builtin_amdgcn_mfma_f32_16x16x32_bf16(a[fi], x[fj], acc[fi][fj], 0,0,0);
        }
        #pragma unroll
        for (int fi=0;fi<4;fi++){
            #pragma unroll
            for (int fj=0;fj<2;fj++){
                int o = o0 + fi*16 + lg*4;
                int n = n0 + nl0 + fj*16 + lr;
                ushort4 u;
                u.x = f2bf(acc[fi][fj].x); u.y = f2bf(acc[fi][fj].y);
                u.z = f2bf(acc[fi][fj].z); u.w = f2bf(acc[fi][fj].w);
                if (mat == 2)
                    *(ushort4*)(f3t + (size_t)(b*NN + n)*CC + o) = u;
                else
                    *(ushort4*)(g12 + (size_t)(b*NN + n)*C2 + mat*CC + o) = u;
            }
        }
    }
}

// ---------------- K3: knn gather-max + combine + BN + residual --------------
__global__ __launch_bounds__(256) void k_gather(
    const float* __restrict__ f,
    const int* __restrict__ qidx,
    const unsigned short* __restrict__ g12,
    const unsigned short* __restrict__ f3t,
    const unsigned short* __restrict__ pe,
    const float* __restrict__ bn_g, const float* __restrict__ bn_b,
    const float* __restrict__ bn_m, const float* __restrict__ bn_v,
    unsigned short* __restrict__ fmidb)
{
    const int lane = threadIdx.x & 63;
    const int wrp  = threadIdx.x >> 6;
    int b, tile;
    xcd_remap(blockIdx.x, b, tile);   // 2048 tiles (of 4 points) per batch
    const int n = tile*4 + wrp;
    const int p = b*NN + n;
    const int* idxp = qidx + (size_t)p*KK;

    uint2 sv = *(const uint2*)(g12 + (size_t)p*C2 + lane*4);
    float s0 = lo16(sv.x), s1 = hi16(sv.x), s2 = lo16(sv.y), s3 = hi16(sv.y);

    float a0=-3.0e38f, a1=-3.0e38f, a2=-3.0e38f, a3=-3.0e38f;
    const unsigned short* gb = g12 + (size_t)b*NN*C2 + lane*4;
    #pragma unroll
    for (int k=0;k<KK;k++){
        int j = idxp[k];
        uint2 gv = *(const uint2*)(gb + (size_t)j*C2);
        a0 = fmaxf(a0, lo16(gv.x)); a1 = fmaxf(a1, hi16(gv.x));
        a2 = fmaxf(a2, lo16(gv.y)); a3 = fmaxf(a3, hi16(gv.y));
    }
    if (lane >= 32){ a0 += s0; a1 += s1; a2 += s2; a3 += s3; }
    float c0v = a0 + __shfl_xor(a0, 32);
    float c1v = a1 + __shfl_xor(a1, 32);
    float c2v = a2 + __shfl_xor(a2, 32);
    float c3v = a3 + __shfl_xor(a3, 32);
    if (lane < 32){
        const int ch = lane*4;
        uint2 f3v = *(const uint2*)(f3t + (size_t)p*CC + ch);
        uint2 pev = *(const uint2*)(pe  + (size_t)p*CC + ch);
        float s[4] = { c0v + lo16(f3v.x), c1v + hi16(f3v.x),
                       c2v + lo16(f3v.y), c3v + hi16(f3v.y) };
        float pv[4] = { lo16(pev.x), hi16(pev.x), lo16(pev.y), hi16(pev.y) };
        float4 g4 = *(const float4*)(bn_g + ch);
        float4 b4 = *(const float4*)(bn_b + ch);
        float4 m4 = *(const float4*)(bn_m + ch);
        float4 v4 = *(const float4*)(bn_v + ch);
        const float gg[4]={g4.x,g4.y,g4.z,g4.w}, bbv[4]={b4.x,b4.y,b4.z,b4.w},
                    mmv[4]={m4.x,m4.y,m4.z,m4.w}, vvv[4]={v4.x,v4.y,v4.z,v4.w};
        const float* fc = f + ((size_t)b*CC + ch)*NN + n;
        float ov[4];
        #pragma unroll
        for (int i=0;i<4;i++){
            float sc = gg[i] / sqrtf(vvv[i] + 1e-5f);
            float bnval = (s[i]-mmv[i])*sc + bbv[i];
            ov[i] = fc[(size_t)i*NN] + bnval + pv[i];
        }
        ushort4 u; u.x=f2bf(ov[0]); u.y=f2bf(ov[1]); u.z=f2bf(ov[2]); u.w=f2bf(ov[3]);
        *(ushort4*)(fmidb + (size_t)p*CC + ch) = u;
    }
}

// ---------------- K4: h2 = gelu(bn(m_w1 @ fmid)) MFMA -----------------------
__global__ __launch_bounds__(256) void k_h2(
    const unsigned short* __restrict__ fmidb,
    const float* __restrict__ w1g,
    const float* __restrict__ bng, const float* __restrict__ bnb,
    const float* __restrict__ bnm, const float* __restrict__ bnv,
    unsigned short* __restrict__ h2)
{
    __shared__ alignas(16) unsigned short Xs[64*128];
    __shared__ alignas(16) unsigned short Ws[128*128];
    __shared__ float s_sc[128], s_sh[128];
    const int tid = threadIdx.x;
    int b, tile;
    xcd_remap(blockIdx.x, b, tile);
    const int n0 = tile * 64;
    const int jh = blockIdx.y;

    #pragma unroll
    for (int p=0;p<4;p++){
        int n = (tid>>4) + p*16;
        int c8 = (tid&15)*8;
        uint4 v = *(const uint4*)(fmidb + (size_t)(b*NN + n0 + n)*CC + c8);
        int off = n*256 + ((c8*2) ^ ((n&7)<<4));
        *(uint4*)((char*)Xs + off) = v;
    }
    const float* Wg = w1g + (size_t)jh*128*CC;
    #pragma unroll 4
    for (int p = 0; p < 16; ++p){
        int o = (tid >> 5) + p*8;
        int c4 = (tid & 31) * 4;
        float4 w = *(const float4*)(Wg + (size_t)o*CC + c4);
        int off = o*256 + ((c4*2) ^ ((o&7)<<4));
        uint2 v; v.x = pk2(w.x, w.y); v.y = pk2(w.z, w.w);
        *(uint2*)((char*)Ws + off) = v;
    }
    if (tid < 128){
        int jg = jh*128 + tid;
        float sc = bng[jg] / sqrtf(bnv[jg] + 1e-5f);
        s_sc[tid] = sc; s_sh[tid] = bnb[jg] - bnm[jg]*sc;
    }
    __syncthreads();

    const int wid = tid >> 6, lane = tid & 63;
    const int lr = lane & 15, lg = lane >> 4;
    const int o0 = (wid >> 1) * 64;
    const int nl0 = (wid & 1) * 32;

    f32x4 acc[4][2];
    #pragma unroll
    for (int fi=0;fi<4;fi++){ acc[fi][0]=(f32x4){0,0,0,0}; acc[fi][1]=(f32x4){0,0,0,0}; }
    #pragma unroll
    for (int kk=0; kk<4; ++kk){
        const int kb = kk*64 + lg*16;
        bf16x8 a[4], x[2];
        #pragma unroll
        for (int fi=0;fi<4;fi++){
            int row = o0 + fi*16 + lr;
            a[fi] = *(const bf16x8*)((const char*)Ws + row*256 + (kb ^ ((row&7)<<4)));
        }
        #pragma unroll
        for (int fj=0;fj<2;fj++){
            int nr = nl0 + fj*16 + lr;
            x[fj] = *(const bf16x8*)((const char*)Xs + nr*256 + (kb ^ ((nr&7)<<4)));
        }
        #pragma unroll
        for (int fi=0;fi<4;fi++)
            #pragma unroll
            for (int fj=0;fj<2;fj++)
                acc[fi][fj] = __builtin_amdgcn_mfma_f32_16x16x32_bf16(a[fi], x[fj], acc[fi][fj], 0,0,0);
    }
    #pragma unroll
    for (int fi=0;fi<4;fi++){
        #pragma unroll
        for (int fj=0;fj<2;fj++){
            int o = o0 + fi*16 + lg*4;
            int n = n0 + nl0 + fj*16 + lr;
            float v0 = gelu(acc[fi][fj].x*s_sc[o+0] + s_sh[o+0]);
            float v1 = gelu(acc[fi][fj].y*s_sc[o+1] + s_sh[o+1]);
            float v2 = gelu(acc[fi][fj].z*s_sc[o+2] + s_sh[o+2]);
            float v3 = gelu(acc[fi][fj].w*s_sc[o+3] + s_sh[o+3]);
            ushort4 u; u.x=f2bf(v0); u.y=f2bf(v1); u.z=f2bf(v2); u.w=f2bf(v3);
            *(ushort4*)(h2 + (size_t)(b*NN + n)*C2 + jh*128 + o) = u;
        }
    }
}

// ---------------- K5: out = fmid + m_w2 @ h2 MFMA (K=256, chunked W) --------
__global__ __launch_bounds__(256) void k_out(
    const unsigned short* __restrict__ h2,
    const unsigned short* __restrict__ fmidb,
    const float* __restrict__ w2g,
    float* __restrict__ out)
{
    __shared__ alignas(16) unsigned short Xs[64*256];
    __shared__ alignas(16) unsigned short Wc[128*64];
    const int tid = threadIdx.x;
    int b, tile;
    xcd_remap(blockIdx.x, b, tile);
    const int n0 = tile * 64;

    #pragma unroll
    for (int p=0;p<8;p++){
        int n = (tid>>5) + p*8;
        int c8 = (tid&31)*8;
        uint4 v = *(const uint4*)(h2 + (size_t)(b*NN + n0 + n)*C2 + c8);
        int off = n*512 + ((c8*2) ^ ((n&7)<<4));
        *(uint4*)((char*)Xs + off) = v;
    }

    const int wid = tid >> 6, lane = tid & 63;
    const int lr = lane & 15, lg = lane >> 4;
    const int o0 = (wid >> 1) * 64;
    const int nl0 = (wid & 1) * 32;

    f32x4 acc[4][2];
    #pragma unroll
    for (int fi=0;fi<4;fi++){ acc[fi][0]=(f32x4){0,0,0,0}; acc[fi][1]=(f32x4){0,0,0,0}; }

    for (int kc=0; kc<4; ++kc){
        __syncthreads();
        #pragma unroll 4
        for (int p=0;p<8;p++){
            int o = (tid>>4) + p*16;
            int c4 = (tid&15)*4;
            float4 w = *(const float4*)(w2g + (size_t)o*C2 + kc*64 + c4);
            int off = o*128 + ((c4*2) ^ ((o&7)<<4));
            uint2 v; v.x=pk2(w.x,w.y); v.y=pk2(w.z,w.w);
            *(uint2*)((char*)Wc + off) = v;
        }
        __syncthreads();
        #pragma unroll
        for (int kk=0; kk<2; ++kk){
            const int kbW = kk*64 + lg*16;
            const int kbX = kc*128 + kk*64 + lg*16;
            bf16x8 a[4], x[2];
            #pragma unroll
            for (int fi=0;fi<4;fi++){
                int row = o0 + fi*16 + lr;
                a[fi] = *(const bf16x8*)((const char*)Wc + row*128 + (kbW ^ ((row&7)<<4)));
            }
            #pragma unroll
            for (int fj=0;fj<2;fj++){
                int nr = nl0 + fj*16 + lr;
                x[fj] = *(const bf16x8*)((const char*)Xs + nr*512 + (kbX ^ ((nr&7)<<4)));
            }
            #pragma unroll
            for (int fi=0;fi<4;fi++)
                #pragma unroll
                for (int fj=0;fj<2;fj++)
                    acc[fi][fj] = __builtin_amdgcn_mfma_f32_16x16x32_bf16(a[fi], x[fj], acc[fi][fj], 0,0,0);
        }
    }
    #pragma unroll
    for (int fi=0;fi<4;fi++){
        #pragma unroll
        for (int fj=0;fj<2;fj++){
            int o = o0 + fi*16 + lg*4;
            int n = n0 + nl0 + fj*16 + lr;
            ushort4 r4 = *(const ushort4*)(fmidb + (size_t)(b*NN + n)*CC + o);
            float* op = out + ((size_t)b*CC + o)*NN + n;
            op[0*(size_t)NN] = b2f(r4.x) + acc[fi][fj].x;
            op[1*(size_t)NN] = b2f(r4.y) + acc[fi][fj].y;
            op[2*(size_t)NN] = b2f(r4.z) + acc[fi][fj].z;
            op[3*(size_t)NN] = b2f(r4.w) + acc[fi][fj].w;
        }
    }
}

extern "C" void kernel_launch(void* const* d_in, const int* in_sizes, int n_in,
                              void* d_out, int out_size, void* d_ws, size_t ws_size,
                              hipStream_t stream)
{
    const float* f      = (const float*)d_in[0];
    const float* dp     = (const float*)d_in[1];
    const int*   qidx   = (const int*)  d_in[2];
    const float* dirs   = (const float*)d_in[3];
    const float* de_w1  = (const float*)d_in[4];
    const float* de_bng = (const float*)d_in[5];
    const float* de_bnb = (const float*)d_in[6];
    const float* de_bnm = (const float*)d_in[7];
    const float* de_bnv = (const float*)d_in[8];
    const float* de_w2  = (const float*)d_in[9];
    const float* de_b2  = (const float*)d_in[10];
    const float* l_w1   = (const float*)d_in[11];
    const float* l_b1   = (const float*)d_in[12];
    const float* l_w2   = (const float*)d_in[13];
    const float* l_b2   = (const float*)d_in[14];
    const float* l_w3   = (const float*)d_in[15];
    const float* l_b3   = (const float*)d_in[16];
    const float* l_bng  = (const float*)d_in[17];
    const float* l_bnb  = (const float*)d_in[18];
    const float* l_bnm  = (const float*)d_in[19];
    const float* l_bnv  = (const float*)d_in[20];
    const float* m_w1   = (const float*)d_in[21];
    const float* m_bng  = (const float*)d_in[22];
    const float* m_bnb  = (const float*)d_in[23];
    const float* m_bnm  = (const float*)d_in[24];
    const float* m_bnv  = (const float*)d_in[25];
    const float* m_w2   = (const float*)d_in[26];

    char* ws = (char*)d_ws;
    // layout (bytes):
    //   g12   bf16(B,N,256): [0,        16777216)
    //   h2    bf16(B,N,256): [0,        16777216)  (aliases g12, dead after k_gather)
    //   pe    bf16(B,N,128): [16777216, 25165824)
    //   f3t   bf16(B,N,128): [25165824, 33554432)
    //   fmidb bf16(B,N,128): [33554432, 41943040)
    unsigned short* g12   = (unsigned short*)(ws + 0);
    unsigned short* h2    = (unsigned short*)(ws + 0);
    unsigned short* pe    = (unsigned short*)(ws + 16777216);
    unsigned short* f3t   = (unsigned short*)(ws + 25165824);
    unsigned short* fmidb = (unsigned short*)(ws + 33554432);

    k_pe<<<dim3(512), dim3(256), 0, stream>>>(dp, dirs, de_w1, de_bng, de_bnb, de_bnm, de_bnv,
                                              de_w2, de_b2, pe);
    k_lin3<<<dim3(512), dim3(256), 0, stream>>>(f, l_w1, l_b1, l_w2, l_b2, l_w3, l_b3, g12, f3t);
    k_gather<<<dim3(8192), dim3(256), 0, stream>>>(f, qidx, g12, f3t, pe,
                                                   l_bng, l_bnb, l_bnm, l_bnv, fmidb);
    k_h2<<<dim3(512,2), dim3(256), 0, stream>>>(fmidb, m_w1, m_bng, m_bnb, m_bnm, m_bnv, h2);
    k_out<<<dim3(512), dim3(256), 0, stream>>>(h2, fmidb, m_w2, (float*)d_out);
}